// Round 1
// baseline (1298.580 us; speedup 1.0000x reference)
//
#include <hip/hip_runtime.h>

// Poisson learning: S = samples@W^T + b; G = S S^T - 1e5 I; A = rowsoftmax(G);
// d == 1 in fp32 (softmax rows sum to 1), so P = A^T, Db = B0.
// ut1 = Db; for t=2..6: ut = A^T ut + Db (+predict at t==3). Output ut6.

#define BM 128
#define BN 128
#define BKK 16

__global__ __launch_bounds__(256) void gemm_nt(
    const float* __restrict__ A, const float* __restrict__ B,
    const float* __restrict__ bias, float* __restrict__ C,
    int M, int N, int K,
    long long sA, long long sB, long long sC, int maskDiag)
{
  A += (long long)blockIdx.z * sA;
  B += (long long)blockIdx.z * sB;
  C += (long long)blockIdx.z * sC;

  __shared__ float As[BKK][BM + 4];
  __shared__ float Bs[BKK][BN + 4];

  const int tid = threadIdx.x;
  const int m0 = blockIdx.y * BM;
  const int n0 = blockIdx.x * BN;
  // global->LDS load mapping: 128 rows x 16 k; 2 threads/row, 8 floats each
  const int lrow = tid >> 1;
  const int loff = (tid & 1) * 8;
  // compute mapping: 16x16 threads, each 8x8 outputs as 2x2 of 4x4
  const int tx = tid & 15;
  const int ty = tid >> 4;

  const float* Arow = A + (size_t)(m0 + lrow) * K + loff;
  const float* Brow = B + (size_t)(n0 + lrow) * K + loff;

  float acc[8][8];
#pragma unroll
  for (int i = 0; i < 8; i++)
#pragma unroll
    for (int j = 0; j < 8; j++) acc[i][j] = 0.f;

  for (int k0 = 0; k0 < K; k0 += BKK) {
    const float4 a0 = *(const float4*)(Arow + k0);
    const float4 a1 = *(const float4*)(Arow + k0 + 4);
    const float4 b0 = *(const float4*)(Brow + k0);
    const float4 b1 = *(const float4*)(Brow + k0 + 4);
    __syncthreads();
    As[loff + 0][lrow] = a0.x; As[loff + 1][lrow] = a0.y;
    As[loff + 2][lrow] = a0.z; As[loff + 3][lrow] = a0.w;
    As[loff + 4][lrow] = a1.x; As[loff + 5][lrow] = a1.y;
    As[loff + 6][lrow] = a1.z; As[loff + 7][lrow] = a1.w;
    Bs[loff + 0][lrow] = b0.x; Bs[loff + 1][lrow] = b0.y;
    Bs[loff + 2][lrow] = b0.z; Bs[loff + 3][lrow] = b0.w;
    Bs[loff + 4][lrow] = b1.x; Bs[loff + 5][lrow] = b1.y;
    Bs[loff + 6][lrow] = b1.z; Bs[loff + 7][lrow] = b1.w;
    __syncthreads();
#pragma unroll
    for (int kk = 0; kk < BKK; kk++) {
      const float4 xa0 = *(const float4*)&As[kk][ty * 4];
      const float4 xa1 = *(const float4*)&As[kk][ty * 4 + 64];
      const float4 xb0 = *(const float4*)&Bs[kk][tx * 4];
      const float4 xb1 = *(const float4*)&Bs[kk][tx * 4 + 64];
      const float av[8] = {xa0.x, xa0.y, xa0.z, xa0.w, xa1.x, xa1.y, xa1.z, xa1.w};
      const float bv[8] = {xb0.x, xb0.y, xb0.z, xb0.w, xb1.x, xb1.y, xb1.z, xb1.w};
#pragma unroll
      for (int i = 0; i < 8; i++)
#pragma unroll
        for (int j = 0; j < 8; j++)
          acc[i][j] = fmaf(av[i], bv[j], acc[i][j]);
    }
  }

#pragma unroll
  for (int i = 0; i < 8; i++) {
    const int m = m0 + ty * 4 + (i & 3) + (i >> 2) * 64;
#pragma unroll
    for (int jh = 0; jh < 2; jh++) {
      const int n = n0 + tx * 4 + jh * 64;
      float4 v;
      v.x = acc[i][jh * 4 + 0];
      v.y = acc[i][jh * 4 + 1];
      v.z = acc[i][jh * 4 + 2];
      v.w = acc[i][jh * 4 + 3];
      if (bias != nullptr) {
        const float4 bb = *(const float4*)(bias + n);
        v.x += bb.x; v.y += bb.y; v.z += bb.z; v.w += bb.w;
      }
      if (maskDiag) {
        if (m == n + 0) v.x -= 1e5f;
        if (m == n + 1) v.y -= 1e5f;
        if (m == n + 2) v.z -= 1e5f;
        if (m == n + 3) v.w -= 1e5f;
      }
      *(float4*)(C + (size_t)m * N + n) = v;
    }
  }
}

// in-place row softmax over 1024 cols, one block (256 thr) per row
__global__ __launch_bounds__(256) void softmax_kernel(float* __restrict__ G)
{
  __shared__ float buf[1024];
  __shared__ float red[4];
  const int tid = threadIdx.x;
  float* g = G + (size_t)blockIdx.x * 1024;

  float mx = -3.0e38f;
  for (int i = tid; i < 1024; i += 256) {
    const float v = g[i];
    buf[i] = v;
    mx = fmaxf(mx, v);
  }
#pragma unroll
  for (int off = 32; off > 0; off >>= 1) mx = fmaxf(mx, __shfl_down(mx, off));
  if ((tid & 63) == 0) red[tid >> 6] = mx;
  __syncthreads();
  mx = fmaxf(fmaxf(red[0], red[1]), fmaxf(red[2], red[3]));
  __syncthreads();  // red reused below

  float sum = 0.f;
  for (int i = tid; i < 1024; i += 256) {
    const float e = __expf(buf[i] - mx);
    buf[i] = e;
    sum += e;
  }
#pragma unroll
  for (int off = 32; off > 0; off >>= 1) sum += __shfl_down(sum, off);
  if ((tid & 63) == 0) red[tid >> 6] = sum;
  __syncthreads();
  const float inv = 1.0f / (red[0] + red[1] + red[2] + red[3]);
  for (int i = tid; i < 1024; i += 256) g[i] = buf[i] * inv;
}

// B0 = (sup - avg) * row_has;  avg = colsum/total, total = sum(row_has)
__global__ __launch_bounds__(256) void make_db_kernel(
    const float* __restrict__ sup, float* __restrict__ Db)
{
  const int L = 1024, Nn = 64;
  const float* s = sup + (size_t)blockIdx.x * L * Nn;
  float* db = Db + (size_t)blockIdx.x * L * Nn;
  __shared__ float rowhas[1024];
  __shared__ float part[4][64];
  __shared__ float tpart[4];
  __shared__ float avg[64];
  __shared__ float totalsh;
  const int tid = threadIdx.x;

  // phase A: row sums -> row_has, partial total
  float tot = 0.f;
  for (int l = tid; l < L; l += 256) {
    float ssum = 0.f;
    for (int n = 0; n < Nn; n++) ssum += s[(size_t)l * Nn + n];
    const float rh = (ssum > 0.5f) ? 1.f : 0.f;
    rowhas[l] = rh;
    tot += rh;
  }
#pragma unroll
  for (int off = 32; off > 0; off >>= 1) tot += __shfl_down(tot, off);
  if ((tid & 63) == 0) tpart[tid >> 6] = tot;

  // phase B partial column sums (coalesced: n = tid&63)
  const int n = tid & 63, seg = tid >> 6;
  float csum = 0.f;
  for (int l = seg * 256; l < seg * 256 + 256; l++) csum += s[(size_t)l * Nn + n];
  part[seg][n] = csum;
  __syncthreads();
  if (tid == 0) totalsh = tpart[0] + tpart[1] + tpart[2] + tpart[3];
  __syncthreads();
  if (tid < 64) avg[tid] = (part[0][tid] + part[1][tid] + part[2][tid] + part[3][tid]) / totalsh;
  __syncthreads();

  // phase C: Db = (sup - avg) * row_has
  for (int idx = tid; idx < L * Nn; idx += 256) {
    const int l = idx >> 6, nn = idx & 63;
    db[idx] = (s[idx] - avg[nn]) * rowhas[l];
  }
}

// Out[l,n] = sum_m A[m,l] * U[m,n] + Db[l,n] (+ Pred[l,n])
__global__ __launch_bounds__(256) void iter_kernel(
    const float* __restrict__ A, const float* __restrict__ U,
    const float* __restrict__ Db, const float* __restrict__ Pred,
    float* __restrict__ Out)
{
  const int L = 1024, Nn = 64;
  const int b = blockIdx.y;
  const int l0 = blockIdx.x * 64;
  const float* Ab = A + (size_t)b * L * L;
  const float* Ub = U + (size_t)b * L * Nn;
  const float* Dbb = Db + (size_t)b * L * Nn;
  const float* Pb = Pred ? Pred + (size_t)b * L * Nn : nullptr;
  float* Ob = Out + (size_t)b * L * Nn;

  __shared__ float As[64][68];  // [m][l]
  __shared__ float Us[64][68];  // [m][n]
  const int tid = threadIdx.x;
  const int tx = tid & 15;   // n group (4 cols)
  const int ty = tid >> 4;   // l group (4 rows)
  const int lr = tid >> 4;       // load row 0..15
  const int lc = (tid & 15) * 4; // load col

  float acc[4][4];
#pragma unroll
  for (int i = 0; i < 4; i++)
#pragma unroll
    for (int j = 0; j < 4; j++) acc[i][j] = 0.f;

  for (int m0 = 0; m0 < L; m0 += 64) {
    __syncthreads();
#pragma unroll
    for (int r = 0; r < 4; r++) {
      const int mm = lr + r * 16;
      *(float4*)&As[mm][lc] = *(const float4*)(Ab + (size_t)(m0 + mm) * L + l0 + lc);
      *(float4*)&Us[mm][lc] = *(const float4*)(Ub + (size_t)(m0 + mm) * Nn + lc);
    }
    __syncthreads();
#pragma unroll
    for (int mm = 0; mm < 64; mm++) {
      const float4 av = *(const float4*)&As[mm][ty * 4];
      const float4 uv = *(const float4*)&Us[mm][tx * 4];
      const float aa[4] = {av.x, av.y, av.z, av.w};
      const float uu[4] = {uv.x, uv.y, uv.z, uv.w};
#pragma unroll
      for (int i = 0; i < 4; i++)
#pragma unroll
        for (int j = 0; j < 4; j++)
          acc[i][j] = fmaf(aa[i], uu[j], acc[i][j]);
    }
  }

#pragma unroll
  for (int i = 0; i < 4; i++) {
    const int l = l0 + ty * 4 + i;
    float4 v;
    v.x = acc[i][0]; v.y = acc[i][1]; v.z = acc[i][2]; v.w = acc[i][3];
    const float4 dv = *(const float4*)(Dbb + (size_t)l * Nn + tx * 4);
    v.x += dv.x; v.y += dv.y; v.z += dv.z; v.w += dv.w;
    if (Pb) {
      const float4 pv = *(const float4*)(Pb + (size_t)l * Nn + tx * 4);
      v.x += pv.x; v.y += pv.y; v.z += pv.z; v.w += pv.w;
    }
    *(float4*)(Ob + (size_t)l * Nn + tx * 4) = v;
  }
}

extern "C" void kernel_launch(void* const* d_in, const int* in_sizes, int n_in,
                              void* d_out, int out_size, void* d_ws, size_t ws_size,
                              hipStream_t stream) {
  const float* samples = (const float*)d_in[0];  // [8,1024,3072]
  const float* label   = (const float*)d_in[1];  // [8,1024,64]
  const float* predict = (const float*)d_in[2];  // [8,1024,64]
  const float* W       = (const float*)d_in[3];  // [1024,3072]
  const float* bproj   = (const float*)d_in[4];  // [1024]
  float* out = (float*)d_out;                    // [8,1024,64]

  char* ws = (char*)d_ws;
  float* S  = (float*)(ws);                                  // 32 MB
  float* A  = (float*)(ws + (size_t)32 * 1024 * 1024);       // 32 MB (G then A in-place)
  float* Db = (float*)(ws + (size_t)64 * 1024 * 1024);       // 2 MB
  float* uA = (float*)(ws + (size_t)66 * 1024 * 1024);       // 2 MB
  float* uB = (float*)(ws + (size_t)68 * 1024 * 1024);       // 2 MB

  const int B = 8, L = 1024, H = 1024, K3 = 3072;
  const long long LL = (long long)L * L;
  const long long LH = (long long)L * H;

  // 1) S = samples @ W^T + b   (M=8192, N=1024, K=3072)
  dim3 g1(H / BN, (B * L) / BM, 1);
  gemm_nt<<<g1, 256, 0, stream>>>(samples, W, bproj, S, B * L, H, K3, 0, 0, 0, 0);

  // 2) G = S S^T - 1e5 I per batch
  dim3 g2(L / BN, L / BM, B);
  gemm_nt<<<g2, 256, 0, stream>>>(S, S, nullptr, A, L, L, H, LH, LH, LL, 1);

  // 3) A = rowsoftmax(G) in place
  softmax_kernel<<<B * L, 256, 0, stream>>>(A);

  // 4) Db (= B0, since d == 1 in fp32)
  make_db_kernel<<<B, 256, 0, stream>>>(label, Db);

  // 5) power iteration: ut1 = Db; t=2..6: ut = A^T ut + Db (+predict at t==3)
  dim3 gi(L / 64, B, 1);
  iter_kernel<<<gi, 256, 0, stream>>>(A, Db, Db, nullptr, uA);   // t=2
  iter_kernel<<<gi, 256, 0, stream>>>(A, uA, Db, predict, uB);   // t=3
  iter_kernel<<<gi, 256, 0, stream>>>(A, uB, Db, nullptr, uA);   // t=4
  iter_kernel<<<gi, 256, 0, stream>>>(A, uA, Db, nullptr, uB);   // t=5
  iter_kernel<<<gi, 256, 0, stream>>>(A, uB, Db, nullptr, out);  // t=6
}

// Round 3
// 540.627 us; speedup vs baseline: 2.4020x; 2.4020x over previous
//
#include <hip/hip_runtime.h>

// Poisson learning via split-bf16 MFMA:
//   S = samples@W^T + b  (fp32 -> hi/lo bf16, 3-pass MFMA)
//   G = S S^T - 1e5 I    (hi/lo bf16 MFMA), A = rowsoftmax(G)
//   d == 1 in fp32 => P = A^T, Db = B0
//   ut1 = Db; t=2..6: ut = A^T ut + Db (+predict at t==3). Output ut6.

typedef __bf16 bf16_t;
typedef bf16_t bf16x4 __attribute__((ext_vector_type(4)));
typedef bf16_t bf16x8 __attribute__((ext_vector_type(8)));
typedef float floatx4 __attribute__((ext_vector_type(4)));

__device__ __forceinline__ void async_copy16(const void* g, void* l) {
  __builtin_amdgcn_global_load_lds(
      (const __attribute__((address_space(1))) void*)g,
      (__attribute__((address_space(3))) void*)l, 16, 0, 0);
}

__device__ __forceinline__ bf16_t hi_of(float x) { return (bf16_t)x; }
__device__ __forceinline__ bf16_t lo_of(float x, bf16_t h) {
  return (bf16_t)(x - (float)h);
}

// fp32 -> (hi, lo) bf16 arrays, float4-vectorized
__global__ __launch_bounds__(256) void split_kernel(
    const float* __restrict__ x, bf16_t* __restrict__ hi,
    bf16_t* __restrict__ lo, int n4)
{
  const int i = blockIdx.x * 256 + threadIdx.x;
  if (i >= n4) return;
  const float4 v = ((const float4*)x)[i];
  bf16x4 h, l;
  bf16_t h0 = hi_of(v.x); h[0] = h0; l[0] = lo_of(v.x, h0);
  bf16_t h1 = hi_of(v.y); h[1] = h1; l[1] = lo_of(v.y, h1);
  bf16_t h2 = hi_of(v.z); h[2] = h2; l[2] = lo_of(v.z, h2);
  bf16_t h3 = hi_of(v.w); h[3] = h3; l[3] = lo_of(v.w, h3);
  *(bf16x4*)(hi + (size_t)i * 4) = h;
  *(bf16x4*)(lo + (size_t)i * 4) = l;
}

// NT GEMM: C[m,n] = sum_k A[m,k]*B[n,k], split-bf16 3-pass MFMA.
// AMODE 0: A is fp32 global (split on the fly, register-prefetched)
// AMODE 1: A is pre-split hi/lo bf16
// CMODE 0: C -> bias add, split-store to Chi/Clo (bf16)
// CMODE 1: C -> fp32 store with -1e5 on diagonal
template <int AMODE, int CMODE>
__global__ __launch_bounds__(256) void gemm_mfma(
    const float* __restrict__ Afp,
    const bf16_t* __restrict__ AhiG, const bf16_t* __restrict__ AloG,
    const bf16_t* __restrict__ BhiG, const bf16_t* __restrict__ BloG,
    const float* __restrict__ bias,
    float* __restrict__ Cf, bf16_t* __restrict__ Chi, bf16_t* __restrict__ Clo,
    int M, int N, int K, long long sA, long long sB, long long sC)
{
  if (AMODE == 1) {
    AhiG += (long long)blockIdx.z * sA; AloG += (long long)blockIdx.z * sA;
    BhiG += (long long)blockIdx.z * sB; BloG += (long long)blockIdx.z * sB;
  }
  if (CMODE == 1) Cf += (long long)blockIdx.z * sC;

  __shared__ __align__(16) bf16_t AsHi[128 * 32];
  __shared__ __align__(16) bf16_t AsLo[128 * 32];
  __shared__ __align__(16) bf16_t BsHi[128 * 32];
  __shared__ __align__(16) bf16_t BsLo[128 * 32];

  const int tid = threadIdx.x;
  const int lane = tid & 63;
  const int wave = tid >> 6;
  const int wm = wave >> 1, wn = wave & 1;
  const int m0 = blockIdx.y * 128;
  const int n0 = blockIdx.x * 128;

  const int fr = lane & 15;          // row within a 16-tile
  const int kg = (lane >> 4) * 8;    // k sub-offset
  const int aoff = (wm * 64 + fr) * 32 + kg;
  const int boff = (wn * 64 + fr) * 32 + kg;

  floatx4 acc[4][4] = {};
  float4 pa[4];

  if (AMODE == 0) {
#pragma unroll
    for (int it = 0; it < 4; ++it) {
      const int c = it * 256 + tid;
      pa[it] = *(const float4*)(Afp + (size_t)(m0 + (c >> 3)) * K + ((c & 7) * 4));
    }
  }

  for (int k0 = 0; k0 < K; k0 += 32) {
    __syncthreads();
    if (AMODE == 0) {
#pragma unroll
      for (int it = 0; it < 4; ++it) {
        const int c = it * 256 + tid;
        const int row = c >> 3, f4 = (c & 7) * 4;
        const float4 v = pa[it];
        bf16x4 h, l;
        bf16_t h0 = hi_of(v.x); h[0] = h0; l[0] = lo_of(v.x, h0);
        bf16_t h1 = hi_of(v.y); h[1] = h1; l[1] = lo_of(v.y, h1);
        bf16_t h2 = hi_of(v.z); h[2] = h2; l[2] = lo_of(v.z, h2);
        bf16_t h3 = hi_of(v.w); h[3] = h3; l[3] = lo_of(v.w, h3);
        *(bf16x4*)&AsHi[row * 32 + f4] = h;
        *(bf16x4*)&AsLo[row * 32 + f4] = l;
      }
    } else {
#pragma unroll
      for (int it = 0; it < 2; ++it) {
        const int cb = it * 256 + wave * 64;   // wave-uniform chunk base
        const int c = cb + lane;
        const int row = c >> 2, kc = (c & 3) * 8;
        const size_t goff = (size_t)(m0 + row) * K + k0 + kc;
        async_copy16(AhiG + goff, (char*)AsHi + (size_t)cb * 16);
        async_copy16(AloG + goff, (char*)AsLo + (size_t)cb * 16);
      }
    }
#pragma unroll
    for (int it = 0; it < 2; ++it) {
      const int cb = it * 256 + wave * 64;
      const int c = cb + lane;
      const int row = c >> 2, kc = (c & 3) * 8;
      const size_t goff = (size_t)(n0 + row) * K + k0 + kc;
      async_copy16(BhiG + goff, (char*)BsHi + (size_t)cb * 16);
      async_copy16(BloG + goff, (char*)BsLo + (size_t)cb * 16);
    }
    __syncthreads();

    if (AMODE == 0 && k0 + 32 < K) {
#pragma unroll
      for (int it = 0; it < 4; ++it) {
        const int c = it * 256 + tid;
        pa[it] = *(const float4*)(Afp + (size_t)(m0 + (c >> 3)) * K + (k0 + 32) + ((c & 7) * 4));
      }
    }

    bf16x8 ah[4], al[4], bh[4], bl[4];
#pragma unroll
    for (int t = 0; t < 4; ++t) {
      ah[t] = *(const bf16x8*)&AsHi[aoff + t * 512];
      al[t] = *(const bf16x8*)&AsLo[aoff + t * 512];
      bh[t] = *(const bf16x8*)&BsHi[boff + t * 512];
      bl[t] = *(const bf16x8*)&BsLo[boff + t * 512];
    }
#pragma unroll
    for (int i = 0; i < 4; ++i)
#pragma unroll
      for (int j = 0; j < 4; ++j) {
        acc[i][j] = __builtin_amdgcn_mfma_f32_16x16x32_bf16(ah[i], bh[j], acc[i][j], 0, 0, 0);
        acc[i][j] = __builtin_amdgcn_mfma_f32_16x16x32_bf16(ah[i], bl[j], acc[i][j], 0, 0, 0);
        acc[i][j] = __builtin_amdgcn_mfma_f32_16x16x32_bf16(al[i], bh[j], acc[i][j], 0, 0, 0);
      }
  }

  // epilogue: C/D layout col=lane&15, row=(lane>>4)*4+reg
  const int mr = (lane >> 4) * 4;
#pragma unroll
  for (int j = 0; j < 4; ++j) {
    const int n = n0 + wn * 64 + j * 16 + fr;
    const float bj = (CMODE == 0) ? bias[n] : 0.f;
#pragma unroll
    for (int i = 0; i < 4; ++i) {
#pragma unroll
      for (int r = 0; r < 4; ++r) {
        const int m = m0 + wm * 64 + i * 16 + mr + r;
        float v = acc[i][j][r];
        if (CMODE == 0) {
          v += bj;
          bf16_t h = hi_of(v);
          Chi[(size_t)m * N + n] = h;
          Clo[(size_t)m * N + n] = lo_of(v, h);
        } else {
          if (m == n) v -= 1e5f;
          Cf[(size_t)m * N + n] = v;
        }
      }
    }
  }
}

// in-place row softmax over 1024 cols, one block (256 thr) per row
__global__ __launch_bounds__(256) void softmax_kernel(float* __restrict__ G)
{
  __shared__ float buf[1024];
  __shared__ float red[4];
  const int tid = threadIdx.x;
  float* g = G + (size_t)blockIdx.x * 1024;

  float mx = -3.0e38f;
  for (int i = tid; i < 1024; i += 256) {
    const float v = g[i];
    buf[i] = v;
    mx = fmaxf(mx, v);
  }
#pragma unroll
  for (int off = 32; off > 0; off >>= 1) mx = fmaxf(mx, __shfl_down(mx, off));
  if ((tid & 63) == 0) red[tid >> 6] = mx;
  __syncthreads();
  mx = fmaxf(fmaxf(red[0], red[1]), fmaxf(red[2], red[3]));
  __syncthreads();

  float sum = 0.f;
  for (int i = tid; i < 1024; i += 256) {
    const float e = __expf(buf[i] - mx);
    buf[i] = e;
    sum += e;
  }
#pragma unroll
  for (int off = 32; off > 0; off >>= 1) sum += __shfl_down(sum, off);
  if ((tid & 63) == 0) red[tid >> 6] = sum;
  __syncthreads();
  const float inv = 1.0f / (red[0] + red[1] + red[2] + red[3]);
  for (int i = tid; i < 1024; i += 256) g[i] = buf[i] * inv;
}

// Db = (sup - avg) * row_has; one block (1024 thr) per batch
__global__ __launch_bounds__(1024) void make_db_kernel(
    const float* __restrict__ sup, float* __restrict__ Db)
{
  const int L = 1024, Nn = 64;
  const float* s = sup + (size_t)blockIdx.x * L * Nn;
  float* db = Db + (size_t)blockIdx.x * L * Nn;
  __shared__ float rowhas[1024];
  __shared__ float cpart[1024];  // [seg 0..15][n 0..63]
  __shared__ float tpart[16];
  __shared__ float avg[64];
  __shared__ float totalsh;
  const int tid = threadIdx.x;

  // row sums: thread t handles row t
  const float4* sr = (const float4*)(s + (size_t)tid * 64);
  float ss = 0.f;
#pragma unroll
  for (int i = 0; i < 16; ++i) { const float4 v = sr[i]; ss += (v.x + v.y) + (v.z + v.w); }
  const float rh = (ss > 0.5f) ? 1.f : 0.f;
  rowhas[tid] = rh;
  float t = rh;
#pragma unroll
  for (int off = 32; off > 0; off >>= 1) t += __shfl_down(t, off);
  if ((tid & 63) == 0) tpart[tid >> 6] = t;

  // partial column sums
  const int n = tid & 63, seg = tid >> 6;
  float cs = 0.f;
  for (int l = seg * 64; l < seg * 64 + 64; ++l) cs += s[(size_t)l * 64 + n];
  cpart[seg * 64 + n] = cs;
  __syncthreads();
  if (tid == 0) { float tt = 0.f; for (int i = 0; i < 16; ++i) tt += tpart[i]; totalsh = tt; }
  __syncthreads();
  if (tid < 64) {
    float a = 0.f;
    for (int i = 0; i < 16; ++i) a += cpart[i * 64 + tid];
    avg[tid] = a / totalsh;
  }
  __syncthreads();

  const float4* s4 = (const float4*)s;
  float4* d4 = (float4*)db;
  for (int i = tid; i < (L * Nn) / 4; i += 1024) {
    float4 v = s4[i];
    const int l = i >> 4;
    const int nb = (i & 15) * 4;
    const float rhl = rowhas[l];
    v.x = (v.x - avg[nb + 0]) * rhl;
    v.y = (v.y - avg[nb + 1]) * rhl;
    v.z = (v.z - avg[nb + 2]) * rhl;
    v.w = (v.w - avg[nb + 3]) * rhl;
    d4[i] = v;
  }
}

// Out[l,n] = sum_m A[m,l] * U[m,n] + Db[l,n] (+ Pred[l,n]); 32-row l blocks
__global__ __launch_bounds__(256) void iter_kernel(
    const float* __restrict__ A, const float* __restrict__ U,
    const float* __restrict__ Db, const float* __restrict__ Pred,
    float* __restrict__ Out)
{
  const int L = 1024, Nn = 64;
  const int b = blockIdx.y;
  const int l0 = blockIdx.x * 32;
  const float* Ab = A + (size_t)b * L * L;
  const float* Ub = U + (size_t)b * L * Nn;
  const float* Dbb = Db + (size_t)b * L * Nn;
  const float* Pb = Pred ? Pred + (size_t)b * L * Nn : nullptr;
  float* Ob = Out + (size_t)b * L * Nn;

  __shared__ float As[64][36];   // [m][l_local]
  __shared__ float Us[64][68];   // [m][n]
  const int tid = threadIdx.x;
  const int tx = tid & 15;       // n group (4 cols)
  const int ty = tid >> 4;       // l group (2 rows)

  float4 acc0 = {0, 0, 0, 0}, acc1 = {0, 0, 0, 0};

  for (int m0 = 0; m0 < L; m0 += 64) {
    __syncthreads();
#pragma unroll
    for (int it = 0; it < 2; ++it) {
      const int c = it * 256 + tid;
      const int mm = c >> 3, lc = (c & 7) * 4;
      *(float4*)&As[mm][lc] = *(const float4*)(Ab + (size_t)(m0 + mm) * L + l0 + lc);
    }
#pragma unroll
    for (int it = 0; it < 4; ++it) {
      const int c = it * 256 + tid;
      const int mm = c >> 4, nc = (c & 15) * 4;
      *(float4*)&Us[mm][nc] = *(const float4*)(Ub + (size_t)(m0 + mm) * Nn + nc);
    }
    __syncthreads();
#pragma unroll
    for (int mm = 0; mm < 64; ++mm) {
      const float2 a = *(const float2*)&As[mm][ty * 2];
      const float4 u = *(const float4*)&Us[mm][tx * 4];
      acc0.x = fmaf(a.x, u.x, acc0.x); acc0.y = fmaf(a.x, u.y, acc0.y);
      acc0.z = fmaf(a.x, u.z, acc0.z); acc0.w = fmaf(a.x, u.w, acc0.w);
      acc1.x = fmaf(a.y, u.x, acc1.x); acc1.y = fmaf(a.y, u.y, acc1.y);
      acc1.z = fmaf(a.y, u.z, acc1.z); acc1.w = fmaf(a.y, u.w, acc1.w);
    }
  }

  const int l = l0 + ty * 2;
  float4 v0 = acc0, v1 = acc1;
  {
    const float4 d0 = *(const float4*)(Dbb + (size_t)l * Nn + tx * 4);
    const float4 d1 = *(const float4*)(Dbb + (size_t)(l + 1) * Nn + tx * 4);
    v0.x += d0.x; v0.y += d0.y; v0.z += d0.z; v0.w += d0.w;
    v1.x += d1.x; v1.y += d1.y; v1.z += d1.z; v1.w += d1.w;
  }
  if (Pb) {
    const float4 p0 = *(const float4*)(Pb + (size_t)l * Nn + tx * 4);
    const float4 p1 = *(const float4*)(Pb + (size_t)(l + 1) * Nn + tx * 4);
    v0.x += p0.x; v0.y += p0.y; v0.z += p0.z; v0.w += p0.w;
    v1.x += p1.x; v1.y += p1.y; v1.z += p1.z; v1.w += p1.w;
  }
  *(float4*)(Ob + (size_t)l * Nn + tx * 4) = v0;
  *(float4*)(Ob + (size_t)(l + 1) * Nn + tx * 4) = v1;
}

extern "C" void kernel_launch(void* const* d_in, const int* in_sizes, int n_in,
                              void* d_out, int out_size, void* d_ws, size_t ws_size,
                              hipStream_t stream) {
  const float* samples = (const float*)d_in[0];  // [8,1024,3072]
  const float* label   = (const float*)d_in[1];  // [8,1024,64]
  const float* predict = (const float*)d_in[2];  // [8,1024,64]
  const float* W       = (const float*)d_in[3];  // [1024,3072]
  const float* bproj   = (const float*)d_in[4];  // [1024]
  float* out = (float*)d_out;                    // [8,1024,64]

  char* ws = (char*)d_ws;
  size_t off = 0;
  bf16_t* Whi = (bf16_t*)(ws + off); off += (size_t)1024 * 3072 * 2;
  bf16_t* Wlo = (bf16_t*)(ws + off); off += (size_t)1024 * 3072 * 2;
  bf16_t* Shi = (bf16_t*)(ws + off); off += (size_t)8192 * 1024 * 2;
  bf16_t* Slo = (bf16_t*)(ws + off); off += (size_t)8192 * 1024 * 2;
  float*  Aw  = (float*)(ws + off);  off += (size_t)8 * 1024 * 1024 * 4;
  float*  Db  = (float*)(ws + off);  off += (size_t)8 * 1024 * 64 * 4;
  float*  uA  = (float*)(ws + off);  off += (size_t)8 * 1024 * 64 * 4;
  float*  uB  = (float*)(ws + off);  off += (size_t)8 * 1024 * 64 * 4;

  const long long LH = 1024LL * 1024;
  const long long LL = 1024LL * 1024;

  // 0) W -> hi/lo bf16
  split_kernel<<<dim3((1024 * 3072 / 4 + 255) / 256), 256, 0, stream>>>(
      W, Whi, Wlo, 1024 * 3072 / 4);

  // 1) S = samples @ W^T + b  (M=8192,N=1024,K=3072), writes S hi/lo
  gemm_mfma<0, 0><<<dim3(8, 64, 1), 256, 0, stream>>>(
      samples, nullptr, nullptr, Whi, Wlo, bproj,
      nullptr, Shi, Slo, 8192, 1024, 3072, 0, 0, 0);

  // 2) G = S S^T - 1e5 I per batch (M=N=K=1024)
  gemm_mfma<1, 1><<<dim3(8, 8, 8), 256, 0, stream>>>(
      nullptr, Shi, Slo, Shi, Slo, nullptr,
      Aw, nullptr, nullptr, 1024, 1024, 1024, LH, LH, LL);

  // 3) A = rowsoftmax(G) in place
  softmax_kernel<<<8 * 1024, 256, 0, stream>>>(Aw);

  // 4) Db
  make_db_kernel<<<8, 1024, 0, stream>>>(label, Db);

  // 5) power iteration
  dim3 gi(32, 8);
  iter_kernel<<<gi, 256, 0, stream>>>(Aw, Db, Db, nullptr, uA);   // t=2
  iter_kernel<<<gi, 256, 0, stream>>>(Aw, uA, Db, predict, uB);   // t=3
  iter_kernel<<<gi, 256, 0, stream>>>(Aw, uB, Db, nullptr, uA);   // t=4
  iter_kernel<<<gi, 256, 0, stream>>>(Aw, uA, Db, nullptr, uB);   // t=5
  iter_kernel<<<gi, 256, 0, stream>>>(Aw, uB, Db, nullptr, out);  // t=6
}

// Round 4
// 510.736 us; speedup vs baseline: 2.5426x; 1.0585x over previous
//
#include <hip/hip_runtime.h>

// Poisson learning via split-fp16 2-pass MFMA:
//   S = samples@W^T + b  (2-pass: a_hi*w_hi + a_hi*w_lo, W scaled x32 pre-split)
//   G = S S^T - 1e5 I    (2-pass: sh*sh + sh*sl), A = rowsoftmax(G)
//   d == 1 in fp32 => P = A^T, Db = B0
//   ut1 = Db; t=2..6: ut = A^T ut + Db (+predict at t==3). Output ut6.

typedef _Float16 f16_t;
typedef f16_t f16x4 __attribute__((ext_vector_type(4)));
typedef f16_t f16x8 __attribute__((ext_vector_type(8)));
typedef float floatx4 __attribute__((ext_vector_type(4)));

__device__ __forceinline__ void async_copy16(const void* g, void* l) {
  __builtin_amdgcn_global_load_lds(
      (const __attribute__((address_space(1))) void*)g,
      (__attribute__((address_space(3))) void*)l, 16, 0, 0);
}

__device__ __forceinline__ f16_t hi_of(float x) { return (f16_t)x; }
__device__ __forceinline__ f16_t lo_of(float x, f16_t h) {
  return (f16_t)(x - (float)h);
}

// fp32 -> (hi, lo) fp16 arrays (scaled), float4-vectorized
__global__ __launch_bounds__(256) void split_kernel(
    const float* __restrict__ x, f16_t* __restrict__ hi,
    f16_t* __restrict__ lo, int n4, float scale)
{
  const int i = blockIdx.x * 256 + threadIdx.x;
  if (i >= n4) return;
  float4 v = ((const float4*)x)[i];
  v.x *= scale; v.y *= scale; v.z *= scale; v.w *= scale;
  f16x4 h, l;
  f16_t h0 = hi_of(v.x); h[0] = h0; l[0] = lo_of(v.x, h0);
  f16_t h1 = hi_of(v.y); h[1] = h1; l[1] = lo_of(v.y, h1);
  f16_t h2 = hi_of(v.z); h[2] = h2; l[2] = lo_of(v.z, h2);
  f16_t h3 = hi_of(v.w); h[3] = h3; l[3] = lo_of(v.w, h3);
  *(f16x4*)(hi + (size_t)i * 4) = h;
  *(f16x4*)(lo + (size_t)i * 4) = l;
}

// NT GEMM: C[m,n] = sum_k A[m,k]*B[n,k], split-fp16 2-pass MFMA
// (ah*bh + ah*bl; A-side lo never needed).
// AMODE 0: A is fp32 global (convert-to-hi on the fly, register-prefetched)
// AMODE 1: A is pre-split hi fp16
// CMODE 0: C -> *cscale, bias add, split-store to Chi/Clo (fp16)
// CMODE 1: C -> fp32 store with -1e5 on diagonal
template <int AMODE, int CMODE>
__global__ __launch_bounds__(256) void gemm_mfma(
    const float* __restrict__ Afp, const f16_t* __restrict__ AhiG,
    const f16_t* __restrict__ BhiG, const f16_t* __restrict__ BloG,
    const float* __restrict__ bias,
    float* __restrict__ Cf, f16_t* __restrict__ Chi, f16_t* __restrict__ Clo,
    int M, int N, int K, long long sA, long long sB, long long sC, float cscale)
{
  if (AMODE == 1) {
    AhiG += (long long)blockIdx.z * sA;
    BhiG += (long long)blockIdx.z * sB;
    BloG += (long long)blockIdx.z * sB;
  }
  if (CMODE == 1) Cf += (long long)blockIdx.z * sC;

  __shared__ __align__(16) f16_t AsHi[128 * 32];
  __shared__ __align__(16) f16_t BsHi[128 * 32];
  __shared__ __align__(16) f16_t BsLo[128 * 32];

  const int tid = threadIdx.x;
  const int lane = tid & 63;
  const int wave = tid >> 6;
  const int wm = wave >> 1, wn = wave & 1;
  const int m0 = blockIdx.y * 128;
  const int n0 = blockIdx.x * 128;

  const int fr = lane & 15;          // row within a 16-tile
  const int kg = (lane >> 4) * 8;    // k sub-offset
  const int aoff = (wm * 64 + fr) * 32 + kg;
  const int boff = (wn * 64 + fr) * 32 + kg;

  floatx4 acc[4][4] = {};
  float4 pa[4];

  if (AMODE == 0) {
#pragma unroll
    for (int it = 0; it < 4; ++it) {
      const int c = it * 256 + tid;
      pa[it] = *(const float4*)(Afp + (size_t)(m0 + (c >> 3)) * K + ((c & 7) * 4));
    }
  }

  for (int k0 = 0; k0 < K; k0 += 32) {
    __syncthreads();
    if (AMODE == 0) {
#pragma unroll
      for (int it = 0; it < 4; ++it) {
        const int c = it * 256 + tid;
        const int row = c >> 3, f4 = (c & 7) * 4;
        const float4 v = pa[it];
        f16x4 h;
        h[0] = hi_of(v.x); h[1] = hi_of(v.y);
        h[2] = hi_of(v.z); h[3] = hi_of(v.w);
        *(f16x4*)&AsHi[row * 32 + f4] = h;
      }
    } else {
#pragma unroll
      for (int it = 0; it < 2; ++it) {
        const int cb = it * 256 + wave * 64;   // wave-uniform chunk base
        const int c = cb + lane;
        const int row = c >> 2, kc = (c & 3) * 8;
        const size_t goff = (size_t)(m0 + row) * K + k0 + kc;
        async_copy16(AhiG + goff, (char*)AsHi + (size_t)cb * 16);
      }
    }
#pragma unroll
    for (int it = 0; it < 2; ++it) {
      const int cb = it * 256 + wave * 64;
      const int c = cb + lane;
      const int row = c >> 2, kc = (c & 3) * 8;
      const size_t goff = (size_t)(n0 + row) * K + k0 + kc;
      async_copy16(BhiG + goff, (char*)BsHi + (size_t)cb * 16);
      async_copy16(BloG + goff, (char*)BsLo + (size_t)cb * 16);
    }
    __syncthreads();

    if (AMODE == 0 && k0 + 32 < K) {
#pragma unroll
      for (int it = 0; it < 4; ++it) {
        const int c = it * 256 + tid;
        pa[it] = *(const float4*)(Afp + (size_t)(m0 + (c >> 3)) * K + (k0 + 32) + ((c & 7) * 4));
      }
    }

    f16x8 ah[4], bh[4], bl[4];
#pragma unroll
    for (int t = 0; t < 4; ++t) {
      ah[t] = *(const f16x8*)&AsHi[aoff + t * 512];
      bh[t] = *(const f16x8*)&BsHi[boff + t * 512];
      bl[t] = *(const f16x8*)&BsLo[boff + t * 512];
    }
#pragma unroll
    for (int i = 0; i < 4; ++i)
#pragma unroll
      for (int j = 0; j < 4; ++j) {
        acc[i][j] = __builtin_amdgcn_mfma_f32_16x16x32_f16(ah[i], bh[j], acc[i][j], 0, 0, 0);
        acc[i][j] = __builtin_amdgcn_mfma_f32_16x16x32_f16(ah[i], bl[j], acc[i][j], 0, 0, 0);
      }
  }

  // epilogue: C/D layout col=lane&15, row=(lane>>4)*4+reg
  const int mr = (lane >> 4) * 4;
#pragma unroll
  for (int j = 0; j < 4; ++j) {
    const int n = n0 + wn * 64 + j * 16 + fr;
    const float bj = (CMODE == 0) ? bias[n] : 0.f;
#pragma unroll
    for (int i = 0; i < 4; ++i) {
#pragma unroll
      for (int r = 0; r < 4; ++r) {
        const int m = m0 + wm * 64 + i * 16 + mr + r;
        float v = acc[i][j][r];
        if (CMODE == 0) {
          v = v * cscale + bj;
          f16_t h = hi_of(v);
          Chi[(size_t)m * N + n] = h;
          Clo[(size_t)m * N + n] = lo_of(v, h);
        } else {
          if (m == n) v -= 1e5f;
          Cf[(size_t)m * N + n] = v;
        }
      }
    }
  }
}

// in-place row softmax over 1024 cols, one block (256 thr) per row
__global__ __launch_bounds__(256) void softmax_kernel(float* __restrict__ G)
{
  __shared__ float buf[1024];
  __shared__ float red[4];
  const int tid = threadIdx.x;
  float* g = G + (size_t)blockIdx.x * 1024;

  float mx = -3.0e38f;
  for (int i = tid; i < 1024; i += 256) {
    const float v = g[i];
    buf[i] = v;
    mx = fmaxf(mx, v);
  }
#pragma unroll
  for (int off = 32; off > 0; off >>= 1) mx = fmaxf(mx, __shfl_down(mx, off));
  if ((tid & 63) == 0) red[tid >> 6] = mx;
  __syncthreads();
  mx = fmaxf(fmaxf(red[0], red[1]), fmaxf(red[2], red[3]));
  __syncthreads();

  float sum = 0.f;
  for (int i = tid; i < 1024; i += 256) {
    const float e = __expf(buf[i] - mx);
    buf[i] = e;
    sum += e;
  }
#pragma unroll
  for (int off = 32; off > 0; off >>= 1) sum += __shfl_down(sum, off);
  if ((tid & 63) == 0) red[tid >> 6] = sum;
  __syncthreads();
  const float inv = 1.0f / (red[0] + red[1] + red[2] + red[3]);
  for (int i = tid; i < 1024; i += 256) g[i] = buf[i] * inv;
}

// Db = (sup - avg) * row_has; one block (1024 thr) per batch
__global__ __launch_bounds__(1024) void make_db_kernel(
    const float* __restrict__ sup, float* __restrict__ Db)
{
  const int L = 1024, Nn = 64;
  const float* s = sup + (size_t)blockIdx.x * L * Nn;
  float* db = Db + (size_t)blockIdx.x * L * Nn;
  __shared__ float rowhas[1024];
  __shared__ float cpart[1024];  // [seg 0..15][n 0..63]
  __shared__ float tpart[16];
  __shared__ float avg[64];
  __shared__ float totalsh;
  const int tid = threadIdx.x;

  const float4* sr = (const float4*)(s + (size_t)tid * 64);
  float ss = 0.f;
#pragma unroll
  for (int i = 0; i < 16; ++i) { const float4 v = sr[i]; ss += (v.x + v.y) + (v.z + v.w); }
  const float rh = (ss > 0.5f) ? 1.f : 0.f;
  rowhas[tid] = rh;
  float t = rh;
#pragma unroll
  for (int off = 32; off > 0; off >>= 1) t += __shfl_down(t, off);
  if ((tid & 63) == 0) tpart[tid >> 6] = t;

  const int n = tid & 63, seg = tid >> 6;
  float cs = 0.f;
  for (int l = seg * 64; l < seg * 64 + 64; ++l) cs += s[(size_t)l * 64 + n];
  cpart[seg * 64 + n] = cs;
  __syncthreads();
  if (tid == 0) { float tt = 0.f; for (int i = 0; i < 16; ++i) tt += tpart[i]; totalsh = tt; }
  __syncthreads();
  if (tid < 64) {
    float a = 0.f;
    for (int i = 0; i < 16; ++i) a += cpart[i * 64 + tid];
    avg[tid] = a / totalsh;
  }
  __syncthreads();

  const float4* s4 = (const float4*)s;
  float4* d4 = (float4*)db;
  for (int i = tid; i < (L * Nn) / 4; i += 1024) {
    float4 v = s4[i];
    const int l = i >> 4;
    const int nb = (i & 15) * 4;
    const float rhl = rowhas[l];
    v.x = (v.x - avg[nb + 0]) * rhl;
    v.y = (v.y - avg[nb + 1]) * rhl;
    v.z = (v.z - avg[nb + 2]) * rhl;
    v.w = (v.w - avg[nb + 3]) * rhl;
    d4[i] = v;
  }
}

// Out[l,n] = sum_m A[m,l]*U[m,n] + Db[l,n] (+Pred); 512 thr, in-block split-K
__global__ __launch_bounds__(512) void iter_kernel(
    const float* __restrict__ A, const float* __restrict__ U,
    const float* __restrict__ Db, const float* __restrict__ Pred,
    float* __restrict__ Out)
{
  const int L = 1024, Nn = 64;
  const int b = blockIdx.y;
  const int l0 = blockIdx.x * 32;
  const float* Ab = A + (size_t)b * L * L;
  const float* Ub = U + (size_t)b * L * Nn;
  const float* Dbb = Db + (size_t)b * L * Nn;
  const float* Pb = Pred ? Pred + (size_t)b * L * Nn : nullptr;
  float* Ob = Out + (size_t)b * L * Nn;

  __shared__ float As[2][64][36];   // [kseg][m][l_local]
  __shared__ float Us[2][64][68];   // [kseg][m][n]
  const int tid = threadIdx.x;
  const int kseg = tid >> 8;     // 0/1: k halves
  const int t = tid & 255;
  const int tx = t & 15;         // n group (4 cols)
  const int ty = t >> 4;         // l group (2 rows)

  float4 acc0 = {0, 0, 0, 0}, acc1 = {0, 0, 0, 0};

  for (int mi = 0; mi < 8; ++mi) {
    const int m0 = kseg * 512 + mi * 64;
    __syncthreads();
#pragma unroll
    for (int it = 0; it < 2; ++it) {
      const int c = it * 256 + t;
      const int mm = c >> 3, lc = (c & 7) * 4;
      *(float4*)&As[kseg][mm][lc] = *(const float4*)(Ab + (size_t)(m0 + mm) * L + l0 + lc);
    }
#pragma unroll
    for (int it = 0; it < 4; ++it) {
      const int c = it * 256 + t;
      const int mm = c >> 4, nc = (c & 15) * 4;
      *(float4*)&Us[kseg][mm][nc] = *(const float4*)(Ub + (size_t)(m0 + mm) * Nn + nc);
    }
    __syncthreads();
#pragma unroll
    for (int mm = 0; mm < 64; ++mm) {
      const float2 a = *(const float2*)&As[kseg][mm][ty * 2];
      const float4 u = *(const float4*)&Us[kseg][mm][tx * 4];
      acc0.x = fmaf(a.x, u.x, acc0.x); acc0.y = fmaf(a.x, u.y, acc0.y);
      acc0.z = fmaf(a.x, u.z, acc0.z); acc0.w = fmaf(a.x, u.w, acc0.w);
      acc1.x = fmaf(a.y, u.x, acc1.x); acc1.y = fmaf(a.y, u.y, acc1.y);
      acc1.z = fmaf(a.y, u.z, acc1.z); acc1.w = fmaf(a.y, u.w, acc1.w);
    }
  }

  // cross-kseg reduction through LDS (reuse As as scratch: need 8 KB)
  __syncthreads();
  float* red = (float*)As;
  if (kseg == 1) {
    float4* r4 = (float4*)(red + t * 8);
    r4[0] = acc0;
    r4[1] = acc1;
  }
  __syncthreads();
  if (kseg == 0) {
    const float4* r4 = (const float4*)(red + t * 8);
    const float4 o0 = r4[0], o1 = r4[1];
    acc0.x += o0.x; acc0.y += o0.y; acc0.z += o0.z; acc0.w += o0.w;
    acc1.x += o1.x; acc1.y += o1.y; acc1.z += o1.z; acc1.w += o1.w;

    const int l = l0 + ty * 2;
    const float4 d0 = *(const float4*)(Dbb + (size_t)l * Nn + tx * 4);
    const float4 d1 = *(const float4*)(Dbb + (size_t)(l + 1) * Nn + tx * 4);
    acc0.x += d0.x; acc0.y += d0.y; acc0.z += d0.z; acc0.w += d0.w;
    acc1.x += d1.x; acc1.y += d1.y; acc1.z += d1.z; acc1.w += d1.w;
    if (Pb) {
      const float4 p0 = *(const float4*)(Pb + (size_t)l * Nn + tx * 4);
      const float4 p1 = *(const float4*)(Pb + (size_t)(l + 1) * Nn + tx * 4);
      acc0.x += p0.x; acc0.y += p0.y; acc0.z += p0.z; acc0.w += p0.w;
      acc1.x += p1.x; acc1.y += p1.y; acc1.z += p1.z; acc1.w += p1.w;
    }
    *(float4*)(Ob + (size_t)l * Nn + tx * 4) = acc0;
    *(float4*)(Ob + (size_t)(l + 1) * Nn + tx * 4) = acc1;
  }
}

extern "C" void kernel_launch(void* const* d_in, const int* in_sizes, int n_in,
                              void* d_out, int out_size, void* d_ws, size_t ws_size,
                              hipStream_t stream) {
  const float* samples = (const float*)d_in[0];  // [8,1024,3072]
  const float* label   = (const float*)d_in[1];  // [8,1024,64]
  const float* predict = (const float*)d_in[2];  // [8,1024,64]
  const float* W       = (const float*)d_in[3];  // [1024,3072]
  const float* bproj   = (const float*)d_in[4];  // [1024]
  float* out = (float*)d_out;                    // [8,1024,64]

  char* ws = (char*)d_ws;
  size_t off = 0;
  f16_t* Whi = (f16_t*)(ws + off); off += (size_t)1024 * 3072 * 2;
  f16_t* Wlo = (f16_t*)(ws + off); off += (size_t)1024 * 3072 * 2;
  f16_t* Shi = (f16_t*)(ws + off); off += (size_t)8192 * 1024 * 2;
  f16_t* Slo = (f16_t*)(ws + off); off += (size_t)8192 * 1024 * 2;
  float*  Aw  = (float*)(ws + off);  off += (size_t)8 * 1024 * 1024 * 4;
  float*  Db  = (float*)(ws + off);  off += (size_t)8 * 1024 * 64 * 4;
  float*  uA  = (float*)(ws + off);  off += (size_t)8 * 1024 * 64 * 4;
  float*  uB  = (float*)(ws + off);  off += (size_t)8 * 1024 * 64 * 4;

  const long long LH = 1024LL * 1024;
  const long long LL = 1024LL * 1024;

  // 0) W*32 -> hi/lo fp16 (scale keeps W-lo out of fp16 subnormal range)
  split_kernel<<<dim3(1024 * 3072 / 4 / 256), 256, 0, stream>>>(
      W, Whi, Wlo, 1024 * 3072 / 4, 32.0f);

  // 1) S = samples @ W^T + b (M=8192,N=1024,K=3072); epilogue x(1/32)
  gemm_mfma<0, 0><<<dim3(8, 64, 1), 256, 0, stream>>>(
      samples, nullptr, Whi, Wlo, bproj,
      nullptr, Shi, Slo, 8192, 1024, 3072, 0, 0, 0, 1.0f / 32.0f);

  // 2) G = S S^T - 1e5 I per batch (M=N=K=1024)
  gemm_mfma<1, 1><<<dim3(8, 8, 8), 256, 0, stream>>>(
      nullptr, Shi, Shi, Slo, nullptr,
      Aw, nullptr, nullptr, 1024, 1024, 1024, LH, LH, LL, 1.0f);

  // 3) A = rowsoftmax(G) in place
  softmax_kernel<<<8 * 1024, 256, 0, stream>>>(Aw);

  // 4) Db
  make_db_kernel<<<8, 1024, 0, stream>>>(label, Db);

  // 5) power iteration
  dim3 gi(32, 8);
  iter_kernel<<<gi, 512, 0, stream>>>(Aw, Db, Db, nullptr, uA);   // t=2
  iter_kernel<<<gi, 512, 0, stream>>>(Aw, uA, Db, predict, uB);   // t=3
  iter_kernel<<<gi, 512, 0, stream>>>(Aw, uB, Db, nullptr, uA);   // t=4
  iter_kernel<<<gi, 512, 0, stream>>>(Aw, uA, Db, nullptr, uB);   // t=5
  iter_kernel<<<gi, 512, 0, stream>>>(Aw, uB, Db, nullptr, out);  // t=6
}

// Round 5
// 436.504 us; speedup vs baseline: 2.9750x; 1.1701x over previous
//
#include <hip/hip_runtime.h>

// Poisson learning, split-fp16 MFMA everywhere:
//   SampH = fp16(samples); S = SampH@(Whi+Wlo)^T + b  (W scaled x32 pre-split)
//   G = S S^T - 1e5 I (2-pass fp16 MFMA, S hi/lo);  G is SYMMETRIC =>
//   At[l][m] = A^T[l][m] = exp(G[l][m]-mx[m])*inv[m]  (row-major, no transpose)
//   d == 1 in fp32 => P = A^T, Db = B0
//   ut1 = Db; t=2..6: ut = At·ut + Db (+predict at t==3); fp16 MFMA iters
//   with U kept transposed (UT fp16 [64][1024]) between iterations.

typedef _Float16 f16_t;
typedef f16_t f16x4 __attribute__((ext_vector_type(4)));
typedef f16_t f16x8 __attribute__((ext_vector_type(8)));
typedef float floatx4 __attribute__((ext_vector_type(4)));

__device__ __forceinline__ void async_copy16(const void* g, void* l) {
  __builtin_amdgcn_global_load_lds(
      (const __attribute__((address_space(1))) void*)g,
      (__attribute__((address_space(3))) void*)l, 16, 0, 0);
}

__device__ __forceinline__ f16_t hi_of(float x) { return (f16_t)x; }
__device__ __forceinline__ f16_t lo_of(float x, f16_t h) {
  return (f16_t)(x - (float)h);
}

// fp32 -> (hi, lo) fp16 (scaled)
__global__ __launch_bounds__(256) void split_kernel(
    const float* __restrict__ x, f16_t* __restrict__ hi,
    f16_t* __restrict__ lo, int n4, float scale)
{
  const int i = blockIdx.x * 256 + threadIdx.x;
  if (i >= n4) return;
  float4 v = ((const float4*)x)[i];
  v.x *= scale; v.y *= scale; v.z *= scale; v.w *= scale;
  f16x4 h, l;
  f16_t h0 = hi_of(v.x); h[0] = h0; l[0] = lo_of(v.x, h0);
  f16_t h1 = hi_of(v.y); h[1] = h1; l[1] = lo_of(v.y, h1);
  f16_t h2 = hi_of(v.z); h[2] = h2; l[2] = lo_of(v.z, h2);
  f16_t h3 = hi_of(v.w); h[3] = h3; l[3] = lo_of(v.w, h3);
  *(f16x4*)(hi + (size_t)i * 4) = h;
  *(f16x4*)(lo + (size_t)i * 4) = l;
}

// fp32 -> fp16 (hi only)
__global__ __launch_bounds__(256) void cvt16_kernel(
    const float* __restrict__ x, f16_t* __restrict__ y, int n4)
{
  const int i = blockIdx.x * 256 + threadIdx.x;
  if (i >= n4) return;
  const float4 v = ((const float4*)x)[i];
  f16x4 h;
  h[0] = (f16_t)v.x; h[1] = (f16_t)v.y; h[2] = (f16_t)v.z; h[3] = (f16_t)v.w;
  *(f16x4*)(y + (size_t)i * 4) = h;
}

// NT GEMM: C[m,n] = sum_k A[m,k]*(Bhi+Blo)[n,k], all-async LDS staging.
// CMODE 0: C -> *cscale + bias, split-store to Chi/Clo (fp16)
// CMODE 1: C -> fp32 store with -1e5 on diagonal
template <int CMODE>
__global__ __launch_bounds__(256) void gemm_mfma(
    const f16_t* __restrict__ AhiG,
    const f16_t* __restrict__ BhiG, const f16_t* __restrict__ BloG,
    const float* __restrict__ bias,
    float* __restrict__ Cf, f16_t* __restrict__ Chi, f16_t* __restrict__ Clo,
    int M, int N, int K, long long sA, long long sB, long long sC, float cscale)
{
  AhiG += (long long)blockIdx.z * sA;
  BhiG += (long long)blockIdx.z * sB;
  BloG += (long long)blockIdx.z * sB;
  if (CMODE == 1) Cf += (long long)blockIdx.z * sC;

  __shared__ __align__(16) f16_t AsHi[128 * 32];
  __shared__ __align__(16) f16_t BsHi[128 * 32];
  __shared__ __align__(16) f16_t BsLo[128 * 32];

  const int tid = threadIdx.x;
  const int lane = tid & 63;
  const int wave = tid >> 6;
  const int wm = wave >> 1, wn = wave & 1;
  const int m0 = blockIdx.y * 128;
  const int n0 = blockIdx.x * 128;

  const int fr = lane & 15;
  const int kg = (lane >> 4) * 8;
  const int aoff = (wm * 64 + fr) * 32 + kg;
  const int boff = (wn * 64 + fr) * 32 + kg;

  floatx4 acc[4][4] = {};

  for (int k0 = 0; k0 < K; k0 += 32) {
    __syncthreads();
#pragma unroll
    for (int it = 0; it < 2; ++it) {
      const int cb = it * 256 + wave * 64;   // wave-uniform chunk base
      const int c = cb + lane;
      const int row = c >> 2, kc = (c & 3) * 8;
      const size_t aoffg = (size_t)(m0 + row) * K + k0 + kc;
      const size_t boffg = (size_t)(n0 + row) * K + k0 + kc;
      async_copy16(AhiG + aoffg, (char*)AsHi + (size_t)cb * 16);
      async_copy16(BhiG + boffg, (char*)BsHi + (size_t)cb * 16);
      async_copy16(BloG + boffg, (char*)BsLo + (size_t)cb * 16);
    }
    __syncthreads();

    f16x8 ah[4], bh[4], bl[4];
#pragma unroll
    for (int t = 0; t < 4; ++t) {
      ah[t] = *(const f16x8*)&AsHi[aoff + t * 512];
      bh[t] = *(const f16x8*)&BsHi[boff + t * 512];
      bl[t] = *(const f16x8*)&BsLo[boff + t * 512];
    }
#pragma unroll
    for (int i = 0; i < 4; ++i)
#pragma unroll
      for (int j = 0; j < 4; ++j) {
        acc[i][j] = __builtin_amdgcn_mfma_f32_16x16x32_f16(ah[i], bh[j], acc[i][j], 0, 0, 0);
        acc[i][j] = __builtin_amdgcn_mfma_f32_16x16x32_f16(ah[i], bl[j], acc[i][j], 0, 0, 0);
      }
  }

  // epilogue: C/D layout col=lane&15, row=(lane>>4)*4+reg
  const int mr = (lane >> 4) * 4;
#pragma unroll
  for (int j = 0; j < 4; ++j) {
    const int n = n0 + wn * 64 + j * 16 + fr;
    const float bj = (CMODE == 0) ? bias[n] : 0.f;
#pragma unroll
    for (int i = 0; i < 4; ++i) {
#pragma unroll
      for (int r = 0; r < 4; ++r) {
        const int m = m0 + wm * 64 + i * 16 + mr + r;
        float v = acc[i][j][r];
        if (CMODE == 0) {
          v = v * cscale + bj;
          f16_t h = hi_of(v);
          Chi[(size_t)m * N + n] = h;
          Clo[(size_t)m * N + n] = lo_of(v, h);
        } else {
          if (m == n) v -= 1e5f;
          Cf[(size_t)m * N + n] = v;
        }
      }
    }
  }
}

// per-row max and 1/sum(exp(g-max)) of G; one block per global row
__global__ __launch_bounds__(256) void rowstats_kernel(
    const float* __restrict__ G, float* __restrict__ mx, float* __restrict__ inv)
{
  __shared__ float red[4];
  const int tid = threadIdx.x;
  const float* g = G + (size_t)blockIdx.x * 1024;
  const float4 v = ((const float4*)g)[tid];

  float m = fmaxf(fmaxf(v.x, v.y), fmaxf(v.z, v.w));
#pragma unroll
  for (int off = 32; off > 0; off >>= 1) m = fmaxf(m, __shfl_down(m, off));
  if ((tid & 63) == 0) red[tid >> 6] = m;
  __syncthreads();
  m = fmaxf(fmaxf(red[0], red[1]), fmaxf(red[2], red[3]));
  __syncthreads();

  float s = __expf(v.x - m) + __expf(v.y - m) + __expf(v.z - m) + __expf(v.w - m);
#pragma unroll
  for (int off = 32; off > 0; off >>= 1) s += __shfl_down(s, off);
  if ((tid & 63) == 0) red[tid >> 6] = s;
  __syncthreads();
  if (tid == 0) {
    mx[blockIdx.x] = m;
    inv[blockIdx.x] = 1.0f / (red[0] + red[1] + red[2] + red[3]);
  }
}

// At[l][m] = exp(G[l][m] - mx[m]) * inv[m]  (valid since G symmetric)
__global__ __launch_bounds__(256) void make_at_kernel(
    const float* __restrict__ G, const float* __restrict__ mx,
    const float* __restrict__ inv, f16_t* __restrict__ At)
{
  const int row = blockIdx.x;           // global row b*1024 + l
  const int b = row >> 10;
  const int tid = threadIdx.x;
  const float4 g = ((const float4*)(G + (size_t)row * 1024))[tid];
  const float4 m = ((const float4*)(mx + b * 1024))[tid];
  const float4 iv = ((const float4*)(inv + b * 1024))[tid];
  f16x4 o;
  o[0] = (f16_t)(__expf(g.x - m.x) * iv.x);
  o[1] = (f16_t)(__expf(g.y - m.y) * iv.y);
  o[2] = (f16_t)(__expf(g.z - m.z) * iv.z);
  o[3] = (f16_t)(__expf(g.w - m.w) * iv.w);
  *(f16x4*)(At + (size_t)row * 1024 + tid * 4) = o;
}

// Db = (sup - avg) * row_has; one block (1024 thr) per batch
__global__ __launch_bounds__(1024) void make_db_kernel(
    const float* __restrict__ sup, float* __restrict__ Db)
{
  const int L = 1024, Nn = 64;
  const float* s = sup + (size_t)blockIdx.x * L * Nn;
  float* db = Db + (size_t)blockIdx.x * L * Nn;
  __shared__ float rowhas[1024];
  __shared__ float cpart[1024];
  __shared__ float tpart[16];
  __shared__ float avg[64];
  __shared__ float totalsh;
  const int tid = threadIdx.x;

  const float4* sr = (const float4*)(s + (size_t)tid * 64);
  float ss = 0.f;
#pragma unroll
  for (int i = 0; i < 16; ++i) { const float4 v = sr[i]; ss += (v.x + v.y) + (v.z + v.w); }
  const float rh = (ss > 0.5f) ? 1.f : 0.f;
  rowhas[tid] = rh;
  float t = rh;
#pragma unroll
  for (int off = 32; off > 0; off >>= 1) t += __shfl_down(t, off);
  if ((tid & 63) == 0) tpart[tid >> 6] = t;

  const int n = tid & 63, seg = tid >> 6;
  float cs = 0.f;
  for (int l = seg * 64; l < seg * 64 + 64; ++l) cs += s[(size_t)l * 64 + n];
  cpart[seg * 64 + n] = cs;
  __syncthreads();
  if (tid == 0) { float tt = 0.f; for (int i = 0; i < 16; ++i) tt += tpart[i]; totalsh = tt; }
  __syncthreads();
  if (tid < 64) {
    float a = 0.f;
    for (int i = 0; i < 16; ++i) a += cpart[i * 64 + tid];
    avg[tid] = a / totalsh;
  }
  __syncthreads();

  const float4* s4 = (const float4*)s;
  float4* d4 = (float4*)db;
  for (int i = tid; i < (L * Nn) / 4; i += 1024) {
    float4 v = s4[i];
    const int l = i >> 4;
    const int nb = (i & 15) * 4;
    const float rhl = rowhas[l];
    v.x = (v.x - avg[nb + 0]) * rhl;
    v.y = (v.y - avg[nb + 1]) * rhl;
    v.z = (v.z - avg[nb + 2]) * rhl;
    v.w = (v.w - avg[nb + 3]) * rhl;
    d4[i] = v;
  }
}

// DbT[b][n][l] = (f16)Db[b][l][n]; grid (16 l-tiles, 8 batches)
__global__ __launch_bounds__(256) void transpose_db_kernel(
    const float* __restrict__ Db, f16_t* __restrict__ DbT)
{
  __shared__ f16_t T[64 * 72];
  const int b = blockIdx.y, l0 = blockIdx.x * 64;
  const int tid = threadIdx.x;
  const float* src = Db + (size_t)b * 1024 * 64;
  f16_t* dst = DbT + (size_t)b * 64 * 1024;
#pragma unroll
  for (int it = 0; it < 4; ++it) {
    const int c = it * 256 + tid;
    const int l = c >> 4, nc = (c & 15) * 4;
    const float4 v = *(const float4*)(src + (size_t)(l0 + l) * 64 + nc);
    T[(nc + 0) * 72 + l] = (f16_t)v.x;
    T[(nc + 1) * 72 + l] = (f16_t)v.y;
    T[(nc + 2) * 72 + l] = (f16_t)v.z;
    T[(nc + 3) * 72 + l] = (f16_t)v.w;
  }
  __syncthreads();
#pragma unroll
  for (int it = 0; it < 2; ++it) {
    const int c = it * 256 + tid;
    const int n = c >> 3, lc = (c & 7) * 8;
    *(f16x8*)(dst + (size_t)n * 1024 + l0 + lc) = *(const f16x8*)&T[n * 72 + lc];
  }
}

// One power-iteration step via MFMA:
//   C[l][n] = sum_m At[l][m] * UT[n][m] + Db[l][n] (+Pred)
//   FINAL: write fp32 OutF[l][n]; else write UTn[n][l] fp16 (LDS transpose).
// grid (16 l-tiles of 64, 8 batches), 256 threads.
template <int PRED, int FINAL>
__global__ __launch_bounds__(256) void iter_mfma(
    const f16_t* __restrict__ At, const f16_t* __restrict__ UT,
    const float* __restrict__ Db, const float* __restrict__ Pred,
    f16_t* __restrict__ UTn, float* __restrict__ OutF)
{
  const int L = 1024, Nn = 64;
  const int b = blockIdx.y, l0 = blockIdx.x * 64;
  At += (size_t)b * L * L;
  UT += (size_t)b * Nn * L;
  Db += (size_t)b * L * Nn;
  if (PRED) Pred += (size_t)b * L * Nn;
  if (FINAL) OutF += (size_t)b * L * Nn; else UTn += (size_t)b * Nn * L;

  // k-split staging: [kk][row][32] keeps 64-B LDS rows (conflict-free frags)
  __shared__ __align__(16) f16_t AtS[2 * 64 * 32];
  __shared__ __align__(16) f16_t UtS[2 * 64 * 32];
  __shared__ f16_t OutS[64 * 72];

  const int tid = threadIdx.x;
  const int lane = tid & 63;
  const int wave = tid >> 6;
  const int fr = lane & 15;
  const int kg = (lane >> 4) * 8;

  floatx4 acc[4] = {};

  for (int m0 = 0; m0 < L; m0 += 64) {
    __syncthreads();
#pragma unroll
    for (int it = 0; it < 2; ++it) {
      const int cb = it * 256 + wave * 64;  // wave-uniform
      const int c = cb + lane;
      const int kk = c >> 8;                 // k-half 0/1
      const int row = (c >> 2) & 63;
      const int kc = kk * 32 + (c & 3) * 8;
      async_copy16(At + (size_t)(l0 + row) * L + m0 + kc, (char*)AtS + (size_t)c * 16 - (size_t)lane * 16 + (size_t)lane * 16);
      async_copy16(UT + (size_t)row * L + m0 + kc, (char*)UtS + (size_t)cb * 16);
    }
    __syncthreads();
#pragma unroll
    for (int kk = 0; kk < 2; ++kk) {
      const f16x8 a = *(const f16x8*)&AtS[kk * 2048 + (wave * 16 + fr) * 32 + kg];
#pragma unroll
      for (int j = 0; j < 4; ++j) {
        const f16x8 bf = *(const f16x8*)&UtS[kk * 2048 + (j * 16 + fr) * 32 + kg];
        acc[j] = __builtin_amdgcn_mfma_f32_16x16x32_f16(a, bf, acc[j], 0, 0, 0);
      }
    }
  }

  const int mr = (lane >> 4) * 4;
#pragma unroll
  for (int j = 0; j < 4; ++j) {
    const int n = j * 16 + fr;
#pragma unroll
    for (int r = 0; r < 4; ++r) {
      const int l = wave * 16 + mr + r;   // local 0..63
      float v = acc[j][r] + Db[(size_t)(l0 + l) * Nn + n];
      if (PRED) v += Pred[(size_t)(l0 + l) * Nn + n];
      if (FINAL) OutF[(size_t)(l0 + l) * Nn + n] = v;
      else OutS[n * 72 + l] = (f16_t)v;
    }
  }
  if (!FINAL) {
    __syncthreads();
#pragma unroll
    for (int it = 0; it < 2; ++it) {
      const int c = it * 256 + tid;
      const int n = c >> 3, lc = (c & 7) * 8;
      *(f16x8*)(UTn + (size_t)n * L + l0 + lc) = *(const f16x8*)&OutS[n * 72 + lc];
    }
  }
}

extern "C" void kernel_launch(void* const* d_in, const int* in_sizes, int n_in,
                              void* d_out, int out_size, void* d_ws, size_t ws_size,
                              hipStream_t stream) {
  const float* samples = (const float*)d_in[0];  // [8,1024,3072]
  const float* label   = (const float*)d_in[1];  // [8,1024,64]
  const float* predict = (const float*)d_in[2];  // [8,1024,64]
  const float* W       = (const float*)d_in[3];  // [1024,3072]
  const float* bproj   = (const float*)d_in[4];  // [1024]
  float* out = (float*)d_out;                    // [8,1024,64]

  char* ws = (char*)d_ws;
  // region A [0, 12.58 MB): Whi/Wlo during projection; small buffers after
  f16_t* Whi = (f16_t*)ws;
  f16_t* Wlo = (f16_t*)(ws + 6291456);
  float* mx  = (float*)ws;                       // after gemm1 (W dead)
  float* inv = (float*)(ws + 32768);
  float* Db  = (float*)(ws + 65536);             // 2 MB
  f16_t* DbT = (f16_t*)(ws + 65536 + 2097152);   // 1 MB
  f16_t* UTa = (f16_t*)(ws + 65536 + 3145728);   // 1 MB
  f16_t* UTb = (f16_t*)(ws + 65536 + 4194304);   // 1 MB
  // region B [12.58, 62.9 MB): SampH (50 MB) during gemm1; G (32 MB) after
  f16_t* SampH = (f16_t*)(ws + 12582912);
  float* G     = (float*)(ws + 12582912);
  // region C [62.9, 96.5 MB): Shi/Slo; At aliases Shi after gemm2
  f16_t* Shi = (f16_t*)(ws + 62914560);
  f16_t* Slo = (f16_t*)(ws + 62914560 + 16777216);
  f16_t* At  = Shi;

  const long long LH = 1024LL * 1024;
  const long long LL = 1024LL * 1024;

  // 0) W*32 -> hi/lo fp16; samples -> fp16
  split_kernel<<<dim3(1024 * 3072 / 4 / 256), 256, 0, stream>>>(
      W, Whi, Wlo, 1024 * 3072 / 4, 32.0f);
  cvt16_kernel<<<dim3(8192 * 3072 / 4 / 256), 256, 0, stream>>>(
      samples, SampH, 8192 * 3072 / 4);

  // 1) S = samples @ W^T + b (M=8192,N=1024,K=3072); epilogue x(1/32)+bias
  gemm_mfma<0><<<dim3(8, 64, 1), 256, 0, stream>>>(
      SampH, Whi, Wlo, bproj, nullptr, Shi, Slo,
      8192, 1024, 3072, 0, 0, 0, 1.0f / 32.0f);

  // 2) G = S S^T - 1e5 I per batch (overwrites SampH region — SampH dead)
  gemm_mfma<1><<<dim3(8, 8, 8), 256, 0, stream>>>(
      Shi, Shi, Slo, nullptr, G, nullptr, nullptr,
      1024, 1024, 1024, LH, LH, LL, 1.0f);

  // 3) row stats + At = softmax^T fp16 (G symmetric; overwrites Shi — dead)
  rowstats_kernel<<<8192, 256, 0, stream>>>(G, mx, inv);
  make_at_kernel<<<8192, 256, 0, stream>>>(G, mx, inv, At);

  // 4) Db fp32 + DbT fp16
  make_db_kernel<<<8, 1024, 0, stream>>>(label, Db);
  transpose_db_kernel<<<dim3(16, 8), 256, 0, stream>>>(Db, DbT);

  // 5) power iteration (MFMA, U transposed fp16 between steps)
  dim3 gi(16, 8);
  iter_mfma<0, 0><<<gi, 256, 0, stream>>>(At, DbT, Db, nullptr, UTa, nullptr); // t=2
  iter_mfma<1, 0><<<gi, 256, 0, stream>>>(At, UTa, Db, predict, UTb, nullptr); // t=3
  iter_mfma<0, 0><<<gi, 256, 0, stream>>>(At, UTb, Db, nullptr, UTa, nullptr); // t=4
  iter_mfma<0, 0><<<gi, 256, 0, stream>>>(At, UTa, Db, nullptr, UTb, nullptr); // t=5
  iter_mfma<0, 1><<<gi, 256, 0, stream>>>(At, UTb, Db, nullptr, nullptr, out); // t=6
}

// Round 6
// 422.446 us; speedup vs baseline: 3.0740x; 1.0333x over previous
//
#include <hip/hip_runtime.h>

// Poisson learning, split-fp16 MFMA everywhere:
//   SampH = fp16(samples); S = SampH@(Whi+Wlo)^T + b  (W scaled x32 pre-split)
//   G = S S^T - 1e5 I (2-pass fp16 MFMA, S hi/lo);  G is SYMMETRIC =>
//   At[l][m] = A^T[l][m] = exp(G[l][m]-mx[m])*inv[m]  (row-major, no transpose)
//   d == 1 in fp32 => P = A^T, Db = B0
//   ut1 = Db; t=2..6: ut = At·ut + Db (+predict at t==3); fp16 MFMA iters,
//   U kept transposed (UT fp16 [64][1024]); iterations split-K over 4 blocks.

typedef _Float16 f16_t;
typedef f16_t f16x4 __attribute__((ext_vector_type(4)));
typedef f16_t f16x8 __attribute__((ext_vector_type(8)));
typedef float floatx4 __attribute__((ext_vector_type(4)));

__device__ __forceinline__ void async_copy16(const void* g, void* l) {
  __builtin_amdgcn_global_load_lds(
      (const __attribute__((address_space(1))) void*)g,
      (__attribute__((address_space(3))) void*)l, 16, 0, 0);
}

__device__ __forceinline__ f16_t hi_of(float x) { return (f16_t)x; }
__device__ __forceinline__ f16_t lo_of(float x, f16_t h) {
  return (f16_t)(x - (float)h);
}

// fp32 -> (hi, lo) fp16 (scaled)
__global__ __launch_bounds__(256) void split_kernel(
    const float* __restrict__ x, f16_t* __restrict__ hi,
    f16_t* __restrict__ lo, int n4, float scale)
{
  const int i = blockIdx.x * 256 + threadIdx.x;
  if (i >= n4) return;
  float4 v = ((const float4*)x)[i];
  v.x *= scale; v.y *= scale; v.z *= scale; v.w *= scale;
  f16x4 h, l;
  f16_t h0 = hi_of(v.x); h[0] = h0; l[0] = lo_of(v.x, h0);
  f16_t h1 = hi_of(v.y); h[1] = h1; l[1] = lo_of(v.y, h1);
  f16_t h2 = hi_of(v.z); h[2] = h2; l[2] = lo_of(v.z, h2);
  f16_t h3 = hi_of(v.w); h[3] = h3; l[3] = lo_of(v.w, h3);
  *(f16x4*)(hi + (size_t)i * 4) = h;
  *(f16x4*)(lo + (size_t)i * 4) = l;
}

// fp32 -> fp16 (hi only)
__global__ __launch_bounds__(256) void cvt16_kernel(
    const float* __restrict__ x, f16_t* __restrict__ y, int n4)
{
  const int i = blockIdx.x * 256 + threadIdx.x;
  if (i >= n4) return;
  const float4 v = ((const float4*)x)[i];
  f16x4 h;
  h[0] = (f16_t)v.x; h[1] = (f16_t)v.y; h[2] = (f16_t)v.z; h[3] = (f16_t)v.w;
  *(f16x4*)(y + (size_t)i * 4) = h;
}

// NT GEMM: C[m,n] = sum_k A[m,k]*(Bhi+Blo)[n,k], all-async LDS staging.
// CMODE 0: C -> *cscale + bias, split-store to Chi/Clo (fp16)
// CMODE 1: C -> fp32 store with -1e5 on diagonal
template <int CMODE>
__global__ __launch_bounds__(256) void gemm_mfma(
    const f16_t* __restrict__ AhiG,
    const f16_t* __restrict__ BhiG, const f16_t* __restrict__ BloG,
    const float* __restrict__ bias,
    float* __restrict__ Cf, f16_t* __restrict__ Chi, f16_t* __restrict__ Clo,
    int M, int N, int K, long long sA, long long sB, long long sC, float cscale)
{
  AhiG += (long long)blockIdx.z * sA;
  BhiG += (long long)blockIdx.z * sB;
  BloG += (long long)blockIdx.z * sB;
  if (CMODE == 1) Cf += (long long)blockIdx.z * sC;

  __shared__ __align__(16) f16_t AsHi[128 * 32];
  __shared__ __align__(16) f16_t BsHi[128 * 32];
  __shared__ __align__(16) f16_t BsLo[128 * 32];

  const int tid = threadIdx.x;
  const int lane = tid & 63;
  const int wave = tid >> 6;
  const int wm = wave >> 1, wn = wave & 1;
  const int m0 = blockIdx.y * 128;
  const int n0 = blockIdx.x * 128;

  const int fr = lane & 15;
  const int kg = (lane >> 4) * 8;
  const int aoff = (wm * 64 + fr) * 32 + kg;
  const int boff = (wn * 64 + fr) * 32 + kg;

  floatx4 acc[4][4] = {};

  for (int k0 = 0; k0 < K; k0 += 32) {
    __syncthreads();
#pragma unroll
    for (int it = 0; it < 2; ++it) {
      const int cb = it * 256 + wave * 64;   // wave-uniform chunk base
      const int c = cb + lane;
      const int row = c >> 2, kc = (c & 3) * 8;
      const size_t aoffg = (size_t)(m0 + row) * K + k0 + kc;
      const size_t boffg = (size_t)(n0 + row) * K + k0 + kc;
      async_copy16(AhiG + aoffg, (char*)AsHi + (size_t)cb * 16);
      async_copy16(BhiG + boffg, (char*)BsHi + (size_t)cb * 16);
      async_copy16(BloG + boffg, (char*)BsLo + (size_t)cb * 16);
    }
    __syncthreads();

    f16x8 ah[4], bh[4], bl[4];
#pragma unroll
    for (int t = 0; t < 4; ++t) {
      ah[t] = *(const f16x8*)&AsHi[aoff + t * 512];
      bh[t] = *(const f16x8*)&BsHi[boff + t * 512];
      bl[t] = *(const f16x8*)&BsLo[boff + t * 512];
    }
#pragma unroll
    for (int i = 0; i < 4; ++i)
#pragma unroll
      for (int j = 0; j < 4; ++j) {
        acc[i][j] = __builtin_amdgcn_mfma_f32_16x16x32_f16(ah[i], bh[j], acc[i][j], 0, 0, 0);
        acc[i][j] = __builtin_amdgcn_mfma_f32_16x16x32_f16(ah[i], bl[j], acc[i][j], 0, 0, 0);
      }
  }

  // epilogue: C/D layout col=lane&15, row=(lane>>4)*4+reg
  const int mr = (lane >> 4) * 4;
#pragma unroll
  for (int j = 0; j < 4; ++j) {
    const int n = n0 + wn * 64 + j * 16 + fr;
    const float bj = (CMODE == 0) ? bias[n] : 0.f;
#pragma unroll
    for (int i = 0; i < 4; ++i) {
#pragma unroll
      for (int r = 0; r < 4; ++r) {
        const int m = m0 + wm * 64 + i * 16 + mr + r;
        float v = acc[i][j][r];
        if (CMODE == 0) {
          v = v * cscale + bj;
          f16_t h = hi_of(v);
          Chi[(size_t)m * N + n] = h;
          Clo[(size_t)m * N + n] = lo_of(v, h);
        } else {
          if (m == n) v -= 1e5f;
          Cf[(size_t)m * N + n] = v;
        }
      }
    }
  }
}

// per-row max and 1/sum(exp(g-max)) of G; one block per global row
__global__ __launch_bounds__(256) void rowstats_kernel(
    const float* __restrict__ G, float* __restrict__ mx, float* __restrict__ inv)
{
  __shared__ float red[4];
  const int tid = threadIdx.x;
  const float* g = G + (size_t)blockIdx.x * 1024;
  const float4 v = ((const float4*)g)[tid];

  float m = fmaxf(fmaxf(v.x, v.y), fmaxf(v.z, v.w));
#pragma unroll
  for (int off = 32; off > 0; off >>= 1) m = fmaxf(m, __shfl_down(m, off));
  if ((tid & 63) == 0) red[tid >> 6] = m;
  __syncthreads();
  m = fmaxf(fmaxf(red[0], red[1]), fmaxf(red[2], red[3]));
  __syncthreads();

  float s = __expf(v.x - m) + __expf(v.y - m) + __expf(v.z - m) + __expf(v.w - m);
#pragma unroll
  for (int off = 32; off > 0; off >>= 1) s += __shfl_down(s, off);
  if ((tid & 63) == 0) red[tid >> 6] = s;
  __syncthreads();
  if (tid == 0) {
    mx[blockIdx.x] = m;
    inv[blockIdx.x] = 1.0f / (red[0] + red[1] + red[2] + red[3]);
  }
}

// At[l][m] = exp(G[l][m] - mx[m]) * inv[m]  (valid since G symmetric)
__global__ __launch_bounds__(256) void make_at_kernel(
    const float* __restrict__ G, const float* __restrict__ mx,
    const float* __restrict__ inv, f16_t* __restrict__ At)
{
  const int row = blockIdx.x;           // global row b*1024 + l
  const int b = row >> 10;
  const int tid = threadIdx.x;
  const float4 g = ((const float4*)(G + (size_t)row * 1024))[tid];
  const float4 m = ((const float4*)(mx + b * 1024))[tid];
  const float4 iv = ((const float4*)(inv + b * 1024))[tid];
  f16x4 o;
  o[0] = (f16_t)(__expf(g.x - m.x) * iv.x);
  o[1] = (f16_t)(__expf(g.y - m.y) * iv.y);
  o[2] = (f16_t)(__expf(g.z - m.z) * iv.z);
  o[3] = (f16_t)(__expf(g.w - m.w) * iv.w);
  *(f16x4*)(At + (size_t)row * 1024 + tid * 4) = o;
}

// Db = (sup - avg) * row_has; one block (1024 thr) per batch
__global__ __launch_bounds__(1024) void make_db_kernel(
    const float* __restrict__ sup, float* __restrict__ Db)
{
  const int L = 1024, Nn = 64;
  const float* s = sup + (size_t)blockIdx.x * L * Nn;
  float* db = Db + (size_t)blockIdx.x * L * Nn;
  __shared__ float rowhas[1024];
  __shared__ float cpart[1024];
  __shared__ float tpart[16];
  __shared__ float avg[64];
  __shared__ float totalsh;
  const int tid = threadIdx.x;

  const float4* sr = (const float4*)(s + (size_t)tid * 64);
  float ss = 0.f;
#pragma unroll
  for (int i = 0; i < 16; ++i) { const float4 v = sr[i]; ss += (v.x + v.y) + (v.z + v.w); }
  const float rh = (ss > 0.5f) ? 1.f : 0.f;
  rowhas[tid] = rh;
  float t = rh;
#pragma unroll
  for (int off = 32; off > 0; off >>= 1) t += __shfl_down(t, off);
  if ((tid & 63) == 0) tpart[tid >> 6] = t;

  const int n = tid & 63, seg = tid >> 6;
  float cs = 0.f;
  for (int l = seg * 64; l < seg * 64 + 64; ++l) cs += s[(size_t)l * 64 + n];
  cpart[seg * 64 + n] = cs;
  __syncthreads();
  if (tid == 0) { float tt = 0.f; for (int i = 0; i < 16; ++i) tt += tpart[i]; totalsh = tt; }
  __syncthreads();
  if (tid < 64) {
    float a = 0.f;
    for (int i = 0; i < 16; ++i) a += cpart[i * 64 + tid];
    avg[tid] = a / totalsh;
  }
  __syncthreads();

  const float4* s4 = (const float4*)s;
  float4* d4 = (float4*)db;
  for (int i = tid; i < (L * Nn) / 4; i += 1024) {
    float4 v = s4[i];
    const int l = i >> 4;
    const int nb = (i & 15) * 4;
    const float rhl = rowhas[l];
    v.x = (v.x - avg[nb + 0]) * rhl;
    v.y = (v.y - avg[nb + 1]) * rhl;
    v.z = (v.z - avg[nb + 2]) * rhl;
    v.w = (v.w - avg[nb + 3]) * rhl;
    d4[i] = v;
  }
}

// DbT[b][n][l] = (f16)Db[b][l][n]; grid (16 l-tiles, 8 batches)
__global__ __launch_bounds__(256) void transpose_db_kernel(
    const float* __restrict__ Db, f16_t* __restrict__ DbT)
{
  __shared__ f16_t T[64 * 72];
  const int b = blockIdx.y, l0 = blockIdx.x * 64;
  const int tid = threadIdx.x;
  const float* src = Db + (size_t)b * 1024 * 64;
  f16_t* dst = DbT + (size_t)b * 64 * 1024;
#pragma unroll
  for (int it = 0; it < 4; ++it) {
    const int c = it * 256 + tid;
    const int l = c >> 4, nc = (c & 15) * 4;
    const float4 v = *(const float4*)(src + (size_t)(l0 + l) * 64 + nc);
    T[(nc + 0) * 72 + l] = (f16_t)v.x;
    T[(nc + 1) * 72 + l] = (f16_t)v.y;
    T[(nc + 2) * 72 + l] = (f16_t)v.z;
    T[(nc + 3) * 72 + l] = (f16_t)v.w;
  }
  __syncthreads();
#pragma unroll
  for (int it = 0; it < 2; ++it) {
    const int c = it * 256 + tid;
    const int n = c >> 3, lc = (c & 7) * 8;
    *(f16x8*)(dst + (size_t)n * 1024 + l0 + lc) = *(const f16x8*)&T[n * 72 + lc];
  }
}

// Partial of one power-iteration step:
//   Part[ks][b][l][n] = sum_{m in ks-quarter} At[l][m] * UT[n][m]
// grid (16 l-tiles, 8 batches, 4 k-splits), 256 threads.
__global__ __launch_bounds__(256) void iter_part(
    const f16_t* __restrict__ At, const f16_t* __restrict__ UT,
    float* __restrict__ Part)
{
  const int L = 1024, Nn = 64;
  const int b = blockIdx.y, l0 = blockIdx.x * 64, ks = blockIdx.z;
  At += (size_t)b * L * L;
  UT += (size_t)b * Nn * L;
  Part += (((size_t)ks * 8 + b) * L) * Nn;

  // k-split staging: [kk][row][32] keeps 64-B LDS rows (conflict-free frags)
  __shared__ __align__(16) f16_t AtS[2 * 64 * 32];
  __shared__ __align__(16) f16_t UtS[2 * 64 * 32];

  const int tid = threadIdx.x;
  const int lane = tid & 63;
  const int wave = tid >> 6;
  const int fr = lane & 15;
  const int kg = (lane >> 4) * 8;

  floatx4 acc[4] = {};

  for (int mi = 0; mi < 4; ++mi) {
    const int m0 = ks * 256 + mi * 64;
    __syncthreads();
#pragma unroll
    for (int it = 0; it < 2; ++it) {
      const int cb = it * 256 + wave * 64;  // wave-uniform
      const int c = cb + lane;
      const int kk = c >> 8;                 // k-half 0/1
      const int row = (c >> 2) & 63;
      const int kc = kk * 32 + (c & 3) * 8;
      async_copy16(At + (size_t)(l0 + row) * L + m0 + kc, (char*)AtS + (size_t)cb * 16);
      async_copy16(UT + (size_t)row * L + m0 + kc, (char*)UtS + (size_t)cb * 16);
    }
    __syncthreads();
#pragma unroll
    for (int kk = 0; kk < 2; ++kk) {
      const f16x8 a = *(const f16x8*)&AtS[kk * 2048 + (wave * 16 + fr) * 32 + kg];
#pragma unroll
      for (int j = 0; j < 4; ++j) {
        const f16x8 bf = *(const f16x8*)&UtS[kk * 2048 + (j * 16 + fr) * 32 + kg];
        acc[j] = __builtin_amdgcn_mfma_f32_16x16x32_f16(a, bf, acc[j], 0, 0, 0);
      }
    }
  }

  const int mr = (lane >> 4) * 4;
#pragma unroll
  for (int j = 0; j < 4; ++j) {
    const int n = j * 16 + fr;
#pragma unroll
    for (int r = 0; r < 4; ++r) {
      const int l = wave * 16 + mr + r;   // local 0..63
      Part[(size_t)(l0 + l) * Nn + n] = acc[j][r];
    }
  }
}

// Finalize one step: sum 4 partials + Db (+Pred);
// FINAL: fp32 OutF[l][n]; else UTn[n][l] fp16 via LDS transpose.
// grid (16 l-tiles, 8 batches), 256 threads.
template <int PRED, int FINAL>
__global__ __launch_bounds__(256) void iter_fin(
    const float* __restrict__ Part, const float* __restrict__ Db,
    const float* __restrict__ Pred, f16_t* __restrict__ UTn,
    float* __restrict__ OutF)
{
  const int L = 1024, Nn = 64;
  const int b = blockIdx.y, l0 = blockIdx.x * 64;
  const size_t base = ((size_t)b * L + l0) * Nn;
  const size_t ksStride = (size_t)8 * L * Nn;
  Db += base;
  if (PRED) Pred += base;

  __shared__ f16_t OutS[64 * 72];
  const int tid = threadIdx.x;

#pragma unroll
  for (int it = 0; it < 4; ++it) {
    const int idx = it * 256 + tid;          // element/4 within 64x64 tile
    const int l = idx >> 4, n4 = (idx & 15) * 4;
    const size_t o = (size_t)l * Nn + n4;
    float4 v = *(const float4*)(Part + base + o);
    const float4 p1 = *(const float4*)(Part + base + ksStride + o);
    const float4 p2 = *(const float4*)(Part + base + 2 * ksStride + o);
    const float4 p3 = *(const float4*)(Part + base + 3 * ksStride + o);
    v.x += p1.x; v.y += p1.y; v.z += p1.z; v.w += p1.w;
    v.x += p2.x; v.y += p2.y; v.z += p2.z; v.w += p2.w;
    v.x += p3.x; v.y += p3.y; v.z += p3.z; v.w += p3.w;
    const float4 d = *(const float4*)(Db + o);
    v.x += d.x; v.y += d.y; v.z += d.z; v.w += d.w;
    if (PRED) {
      const float4 p = *(const float4*)(Pred + o);
      v.x += p.x; v.y += p.y; v.z += p.z; v.w += p.w;
    }
    if (FINAL) {
      *(float4*)(OutF + base + o) = v;
    } else {
      OutS[(n4 + 0) * 72 + l] = (f16_t)v.x;
      OutS[(n4 + 1) * 72 + l] = (f16_t)v.y;
      OutS[(n4 + 2) * 72 + l] = (f16_t)v.z;
      OutS[(n4 + 3) * 72 + l] = (f16_t)v.w;
    }
  }
  if (!FINAL) {
    __syncthreads();
    f16_t* dst = UTn + (size_t)b * Nn * L;
#pragma unroll
    for (int it = 0; it < 2; ++it) {
      const int c = it * 256 + tid;
      const int n = c >> 3, lc = (c & 7) * 8;
      *(f16x8*)(dst + (size_t)n * L + l0 + lc) = *(const f16x8*)&OutS[n * 72 + lc];
    }
  }
}

extern "C" void kernel_launch(void* const* d_in, const int* in_sizes, int n_in,
                              void* d_out, int out_size, void* d_ws, size_t ws_size,
                              hipStream_t stream) {
  const float* samples = (const float*)d_in[0];  // [8,1024,3072]
  const float* label   = (const float*)d_in[1];  // [8,1024,64]
  const float* predict = (const float*)d_in[2];  // [8,1024,64]
  const float* W       = (const float*)d_in[3];  // [1024,3072]
  const float* bproj   = (const float*)d_in[4];  // [1024]
  float* out = (float*)d_out;                    // [8,1024,64]

  char* ws = (char*)d_ws;
  // region A [0, 12.58 MB): Whi/Wlo during projection; small buffers after
  f16_t* Whi = (f16_t*)ws;
  f16_t* Wlo = (f16_t*)(ws + 6291456);
  float* mx  = (float*)ws;                       // after gemm1 (W dead)
  float* inv = (float*)(ws + 32768);
  float* Db  = (float*)(ws + 65536);             // 2 MB
  f16_t* DbT = (f16_t*)(ws + 65536 + 2097152);   // 1 MB
  f16_t* UTa = (f16_t*)(ws + 65536 + 3145728);   // 1 MB
  f16_t* UTb = (f16_t*)(ws + 65536 + 4194304);   // 1 MB
  // region B [12.58, 62.9 MB): SampH (50 MB) during gemm1; G (32 MB) after
  f16_t* SampH = (f16_t*)(ws + 12582912);
  float* G     = (float*)(ws + 12582912);
  // region C [62.9, 96.5 MB): Shi/Slo; At aliases Shi, Part aliases Slo
  f16_t* Shi = (f16_t*)(ws + 62914560);
  f16_t* Slo = (f16_t*)(ws + 62914560 + 16777216);
  f16_t* At  = Shi;
  float* Part = (float*)Slo;                     // 8 MB (Slo dead after gemm2)

  const long long LH = 1024LL * 1024;
  const long long LL = 1024LL * 1024;

  // 0) W*32 -> hi/lo fp16; samples -> fp16
  split_kernel<<<dim3(1024 * 3072 / 4 / 256), 256, 0, stream>>>(
      W, Whi, Wlo, 1024 * 3072 / 4, 32.0f);
  cvt16_kernel<<<dim3(8192 * 3072 / 4 / 256), 256, 0, stream>>>(
      samples, SampH, 8192 * 3072 / 4);

  // 1) S = samples @ W^T + b (M=8192,N=1024,K=3072); epilogue x(1/32)+bias
  gemm_mfma<0><<<dim3(8, 64, 1), 256, 0, stream>>>(
      SampH, Whi, Wlo, bproj, nullptr, Shi, Slo,
      8192, 1024, 3072, 0, 0, 0, 1.0f / 32.0f);

  // 2) G = S S^T - 1e5 I per batch (overwrites SampH region — SampH dead)
  gemm_mfma<1><<<dim3(8, 8, 8), 256, 0, stream>>>(
      Shi, Shi, Slo, nullptr, G, nullptr, nullptr,
      1024, 1024, 1024, LH, LH, LL, 1.0f);

  // 3) row stats + At = softmax^T fp16 (G symmetric; overwrites Shi — dead)
  rowstats_kernel<<<8192, 256, 0, stream>>>(G, mx, inv);
  make_at_kernel<<<8192, 256, 0, stream>>>(G, mx, inv, At);

  // 4) Db fp32 + DbT fp16
  make_db_kernel<<<8, 1024, 0, stream>>>(label, Db);
  transpose_db_kernel<<<dim3(16, 8), 256, 0, stream>>>(Db, DbT);

  // 5) power iteration: each step = split-K partial + finalize
  dim3 gp(16, 8, 4), gf(16, 8);
  iter_part<<<gp, 256, 0, stream>>>(At, DbT, Part);                     // t=2
  iter_fin<0, 0><<<gf, 256, 0, stream>>>(Part, Db, nullptr, UTa, nullptr);
  iter_part<<<gp, 256, 0, stream>>>(At, UTa, Part);                     // t=3
  iter_fin<1, 0><<<gf, 256, 0, stream>>>(Part, Db, predict, UTb, nullptr);
  iter_part<<<gp, 256, 0, stream>>>(At, UTb, Part);                     // t=4
  iter_fin<0, 0><<<gf, 256, 0, stream>>>(Part, Db, nullptr, UTa, nullptr);
  iter_part<<<gp, 256, 0, stream>>>(At, UTa, Part);                     // t=5
  iter_fin<0, 0><<<gf, 256, 0, stream>>>(Part, Db, nullptr, UTb, nullptr);
  iter_part<<<gp, 256, 0, stream>>>(At, UTb, Part);                     // t=6
  iter_fin<0, 1><<<gf, 256, 0, stream>>>(Part, Db, nullptr, nullptr, out);
}

// Round 9
// 420.763 us; speedup vs baseline: 3.0862x; 1.0040x over previous
//
#include <hip/hip_runtime.h>

// Poisson learning, split-fp16 MFMA:
//   prep: W*32 -> Whi/Wlo fp16; samples -> fp16
//   gemm1: S = SampH@(Whi+Wlo)^T + b  (2-pass MFMA, BK=64)
//   gemm2: G = S S^T - 1e5 I  (S hi/lo 2-pass, BK=64); G SYMMETRIC =>
//   At[l][m] = exp(G[l][m]-mx[m])*inv[m]  (COLUMN stats mx[m],inv[m] —
//   two-pass: rowstats then make_at; single-pass row-stats variant is A not A^T)
//   d == 1 in fp32 => P = A^T, Db = B0
//   5 iterations: split-K MFMA partials + finalize (UT fp16 between steps).

typedef _Float16 f16_t;
typedef f16_t f16x4 __attribute__((ext_vector_type(4)));
typedef f16_t f16x8 __attribute__((ext_vector_type(8)));
typedef float floatx4 __attribute__((ext_vector_type(4)));

__device__ __forceinline__ void async_copy16(const void* g, void* l) {
  __builtin_amdgcn_global_load_lds(
      (const __attribute__((address_space(1))) void*)g,
      (__attribute__((address_space(3))) void*)l, 16, 0, 0);
}

__device__ __forceinline__ f16_t hi_of(float x) { return (f16_t)x; }
__device__ __forceinline__ f16_t lo_of(float x, f16_t h) {
  return (f16_t)(x - (float)h);
}

// blocks [0,3072): W*32 -> hi/lo.  blocks [3072,27648): samples -> fp16
__global__ __launch_bounds__(256) void prep_kernel(
    const float* __restrict__ W, f16_t* __restrict__ Whi, f16_t* __restrict__ Wlo,
    const float* __restrict__ samples, f16_t* __restrict__ SampH)
{
  const int bx = blockIdx.x, tid = threadIdx.x;
  if (bx < 3072) {
    const int i = bx * 256 + tid;
    float4 v = ((const float4*)W)[i];
    v.x *= 32.f; v.y *= 32.f; v.z *= 32.f; v.w *= 32.f;
    f16x4 h, l;
    f16_t h0 = hi_of(v.x); h[0] = h0; l[0] = lo_of(v.x, h0);
    f16_t h1 = hi_of(v.y); h[1] = h1; l[1] = lo_of(v.y, h1);
    f16_t h2 = hi_of(v.z); h[2] = h2; l[2] = lo_of(v.z, h2);
    f16_t h3 = hi_of(v.w); h[3] = h3; l[3] = lo_of(v.w, h3);
    *(f16x4*)(Whi + (size_t)i * 4) = h;
    *(f16x4*)(Wlo + (size_t)i * 4) = l;
  } else {
    const int i = (bx - 3072) * 256 + tid;
    const float4 v = ((const float4*)samples)[i];
    f16x4 h;
    h[0] = (f16_t)v.x; h[1] = (f16_t)v.y; h[2] = (f16_t)v.z; h[3] = (f16_t)v.w;
    *(f16x4*)(SampH + (size_t)i * 4) = h;
  }
}

// NT GEMM: C[m,n] = sum_k A[m,k]*(Bhi+Blo)[n,k], BK=64 two-plane staging.
// Accumulation order identical to two successive BK=32 steps.
// CMODE 0: C -> *cscale + bias, split-store Chi/Clo.  CMODE 1: fp32, -1e5 diag.
template <int CMODE>
__global__ __launch_bounds__(256) void gemm_mfma(
    const f16_t* __restrict__ AhiG,
    const f16_t* __restrict__ BhiG, const f16_t* __restrict__ BloG,
    const float* __restrict__ bias,
    float* __restrict__ Cf, f16_t* __restrict__ Chi, f16_t* __restrict__ Clo,
    int M, int N, int K, long long sA, long long sB, long long sC, float cscale)
{
  AhiG += (long long)blockIdx.z * sA;
  BhiG += (long long)blockIdx.z * sB;
  BloG += (long long)blockIdx.z * sB;
  if (CMODE == 1) Cf += (long long)blockIdx.z * sC;

  // [kk][row][32] planes: 64-B rows (same bank behavior as BK=32 layout)
  __shared__ __align__(16) f16_t AsHi[2 * 128 * 32];
  __shared__ __align__(16) f16_t BsHi[2 * 128 * 32];
  __shared__ __align__(16) f16_t BsLo[2 * 128 * 32];

  const int tid = threadIdx.x;
  const int lane = tid & 63;
  const int wave = tid >> 6;
  const int wm = wave >> 1, wn = wave & 1;
  const int m0 = blockIdx.y * 128;
  const int n0 = blockIdx.x * 128;

  const int fr = lane & 15;
  const int kg = (lane >> 4) * 8;
  const int aoff = (wm * 64 + fr) * 32 + kg;
  const int boff = (wn * 64 + fr) * 32 + kg;

  floatx4 acc[4][4] = {};

  for (int k0 = 0; k0 < K; k0 += 64) {
    __syncthreads();
#pragma unroll
    for (int it = 0; it < 4; ++it) {
      const int cb = it * 256 + wave * 64;   // wave-uniform chunk base
      const int c = cb + lane;
      const int kk = c >> 9;                  // k-plane 0/1 (wave-uniform)
      const int row = (c >> 2) & 127;
      const int kc = kk * 32 + (c & 3) * 8;
      const size_t ga = (size_t)(m0 + row) * K + k0 + kc;
      const size_t gb = (size_t)(n0 + row) * K + k0 + kc;
      async_copy16(AhiG + ga, (char*)AsHi + (size_t)cb * 16);
      async_copy16(BhiG + gb, (char*)BsHi + (size_t)cb * 16);
      async_copy16(BloG + gb, (char*)BsLo + (size_t)cb * 16);
    }
    __syncthreads();

#pragma unroll
    for (int kk = 0; kk < 2; ++kk) {
      f16x8 ah[4], bh[4], bl[4];
#pragma unroll
      for (int t = 0; t < 4; ++t) {
        ah[t] = *(const f16x8*)&AsHi[kk * 4096 + aoff + t * 512];
        bh[t] = *(const f16x8*)&BsHi[kk * 4096 + boff + t * 512];
        bl[t] = *(const f16x8*)&BsLo[kk * 4096 + boff + t * 512];
      }
#pragma unroll
      for (int i = 0; i < 4; ++i)
#pragma unroll
        for (int j = 0; j < 4; ++j) {
          acc[i][j] = __builtin_amdgcn_mfma_f32_16x16x32_f16(ah[i], bh[j], acc[i][j], 0, 0, 0);
          acc[i][j] = __builtin_amdgcn_mfma_f32_16x16x32_f16(ah[i], bl[j], acc[i][j], 0, 0, 0);
        }
    }
  }

  const int mr = (lane >> 4) * 4;
#pragma unroll
  for (int j = 0; j < 4; ++j) {
    const int n = n0 + wn * 64 + j * 16 + fr;
    const float bj = (CMODE == 0) ? bias[n] : 0.f;
#pragma unroll
    for (int i = 0; i < 4; ++i) {
#pragma unroll
      for (int r = 0; r < 4; ++r) {
        const int m = m0 + wm * 64 + i * 16 + mr + r;
        float v = acc[i][j][r];
        if (CMODE == 0) {
          v = v * cscale + bj;
          f16_t h = hi_of(v);
          Chi[(size_t)m * N + n] = h;
          Clo[(size_t)m * N + n] = lo_of(v, h);
        } else {
          if (m == n) v -= 1e5f;
          Cf[(size_t)m * N + n] = v;
        }
      }
    }
  }
}

// per-row max and 1/sum(exp(g-max)) of G; one block per global row
__global__ __launch_bounds__(256) void rowstats_kernel(
    const float* __restrict__ G, float* __restrict__ mx, float* __restrict__ inv)
{
  __shared__ float red[4];
  const int tid = threadIdx.x;
  const float* g = G + (size_t)blockIdx.x * 1024;
  const float4 v = ((const float4*)g)[tid];

  float m = fmaxf(fmaxf(v.x, v.y), fmaxf(v.z, v.w));
#pragma unroll
  for (int off = 32; off > 0; off >>= 1) m = fmaxf(m, __shfl_down(m, off));
  if ((tid & 63) == 0) red[tid >> 6] = m;
  __syncthreads();
  m = fmaxf(fmaxf(red[0], red[1]), fmaxf(red[2], red[3]));
  __syncthreads();

  float s = __expf(v.x - m) + __expf(v.y - m) + __expf(v.z - m) + __expf(v.w - m);
#pragma unroll
  for (int off = 32; off > 0; off >>= 1) s += __shfl_down(s, off);
  if ((tid & 63) == 0) red[tid >> 6] = s;
  __syncthreads();
  if (tid == 0) {
    mx[blockIdx.x] = m;
    inv[blockIdx.x] = 1.0f / (red[0] + red[1] + red[2] + red[3]);
  }
}

// At[l][m] = exp(G[l][m] - mx[m]) * inv[m]  (COLUMN stats; valid since G sym)
__global__ __launch_bounds__(256) void make_at_kernel(
    const float* __restrict__ G, const float* __restrict__ mx,
    const float* __restrict__ inv, f16_t* __restrict__ At)
{
  const int row = blockIdx.x;           // global row b*1024 + l
  const int b = row >> 10;
  const int tid = threadIdx.x;
  const float4 g = ((const float4*)(G + (size_t)row * 1024))[tid];
  const float4 m = ((const float4*)(mx + b * 1024))[tid];
  const float4 iv = ((const float4*)(inv + b * 1024))[tid];
  f16x4 o;
  o[0] = (f16_t)(__expf(g.x - m.x) * iv.x);
  o[1] = (f16_t)(__expf(g.y - m.y) * iv.y);
  o[2] = (f16_t)(__expf(g.z - m.z) * iv.z);
  o[3] = (f16_t)(__expf(g.w - m.w) * iv.w);
  *(f16x4*)(At + (size_t)row * 1024 + tid * 4) = o;
}

// Db = (sup - avg) * row_has, plus DbT fp16; one block (1024 thr) per batch
__global__ __launch_bounds__(1024) void make_db_kernel(
    const float* __restrict__ sup, float* __restrict__ Db, f16_t* __restrict__ DbT)
{
  const int L = 1024, Nn = 64;
  const float* s = sup + (size_t)blockIdx.x * L * Nn;
  float* db = Db + (size_t)blockIdx.x * L * Nn;
  f16_t* dbt = DbT + (size_t)blockIdx.x * L * Nn;
  __shared__ float rowhas[1024];
  __shared__ float cpart[1024];
  __shared__ float tpart[16];
  __shared__ float avg[64];
  __shared__ float totalsh;
  const int tid = threadIdx.x;

  const float4* sr = (const float4*)(s + (size_t)tid * 64);
  float ss = 0.f;
#pragma unroll
  for (int i = 0; i < 16; ++i) { const float4 v = sr[i]; ss += (v.x + v.y) + (v.z + v.w); }
  const float rh = (ss > 0.5f) ? 1.f : 0.f;
  rowhas[tid] = rh;
  float t = rh;
#pragma unroll
  for (int off = 32; off > 0; off >>= 1) t += __shfl_down(t, off);
  if ((tid & 63) == 0) tpart[tid >> 6] = t;

  const int n = tid & 63, seg = tid >> 6;
  float cs = 0.f;
  for (int l = seg * 64; l < seg * 64 + 64; ++l) cs += s[(size_t)l * 64 + n];
  cpart[seg * 64 + n] = cs;
  __syncthreads();
  if (tid == 0) { float tt = 0.f; for (int i = 0; i < 16; ++i) tt += tpart[i]; totalsh = tt; }
  __syncthreads();
  if (tid < 64) {
    float a = 0.f;
    for (int i = 0; i < 16; ++i) a += cpart[i * 64 + tid];
    avg[tid] = a / totalsh;
  }
  __syncthreads();

  const float4* s4 = (const float4*)s;
  float4* d4 = (float4*)db;
  for (int i = tid; i < (L * Nn) / 4; i += 1024) {
    float4 v = s4[i];
    const int l = i >> 4;
    const int nb = (i & 15) * 4;
    const float rhl = rowhas[l];
    v.x = (v.x - avg[nb + 0]) * rhl;
    v.y = (v.y - avg[nb + 1]) * rhl;
    v.z = (v.z - avg[nb + 2]) * rhl;
    v.w = (v.w - avg[nb + 3]) * rhl;
    d4[i] = v;
  }
  // DbT[n][l] = (f16)Db[l][n]
  for (int i = tid; i < L * Nn; i += 1024) {
    const int n2 = i >> 10, l2 = i & 1023;
    dbt[i] = (f16_t)((s[(size_t)l2 * 64 + n2] - avg[n2]) * rowhas[l2]);
  }
}

// Partial of one power-iteration step:
//   Part[ks][b][l][n] = sum_{m in ks-quarter} At[l][m] * UT[n][m]
// grid (16 l-tiles, 8 batches, 4 k-splits), 256 threads.
__global__ __launch_bounds__(256) void iter_part(
    const f16_t* __restrict__ At, const f16_t* __restrict__ UT,
    float* __restrict__ Part)
{
  const int L = 1024, Nn = 64;
  const int b = blockIdx.y, l0 = blockIdx.x * 64, ks = blockIdx.z;
  At += (size_t)b * L * L;
  UT += (size_t)b * Nn * L;
  Part += (((size_t)ks * 8 + b) * L) * Nn;

  __shared__ __align__(16) f16_t AtS[2 * 64 * 32];
  __shared__ __align__(16) f16_t UtS[2 * 64 * 32];

  const int tid = threadIdx.x;
  const int lane = tid & 63;
  const int wave = tid >> 6;
  const int fr = lane & 15;
  const int kg = (lane >> 4) * 8;

  floatx4 acc[4] = {};

  for (int mi = 0; mi < 4; ++mi) {
    const int m0 = ks * 256 + mi * 64;
    __syncthreads();
#pragma unroll
    for (int it = 0; it < 2; ++it) {
      const int cb = it * 256 + wave * 64;  // wave-uniform
      const int c = cb + lane;
      const int kk = c >> 8;
      const int row = (c >> 2) & 63;
      const int kc = kk * 32 + (c & 3) * 8;
      async_copy16(At + (size_t)(l0 + row) * L + m0 + kc, (char*)AtS + (size_t)cb * 16);
      async_copy16(UT + (size_t)row * L + m0 + kc, (char*)UtS + (size_t)cb * 16);
    }
    __syncthreads();
#pragma unroll
    for (int kk = 0; kk < 2; ++kk) {
      const f16x8 a = *(const f16x8*)&AtS[kk * 2048 + (wave * 16 + fr) * 32 + kg];
#pragma unroll
      for (int j = 0; j < 4; ++j) {
        const f16x8 bf = *(const f16x8*)&UtS[kk * 2048 + (j * 16 + fr) * 32 + kg];
        acc[j] = __builtin_amdgcn_mfma_f32_16x16x32_f16(a, bf, acc[j], 0, 0, 0);
      }
    }
  }

  const int mr = (lane >> 4) * 4;
#pragma unroll
  for (int j = 0; j < 4; ++j) {
    const int n = j * 16 + fr;
#pragma unroll
    for (int r = 0; r < 4; ++r) {
      const int l = wave * 16 + mr + r;
      Part[(size_t)(l0 + l) * Nn + n] = acc[j][r];
    }
  }
}

// Finalize one step: sum 4 partials + Db (+Pred);
// FINAL: fp32 OutF[l][n]; else UTn[n][l] fp16 via LDS transpose.
template <int PRED, int FINAL>
__global__ __launch_bounds__(256) void iter_fin(
    const float* __restrict__ Part, const float* __restrict__ Db,
    const float* __restrict__ Pred, f16_t* __restrict__ UTn,
    float* __restrict__ OutF)
{
  const int L = 1024, Nn = 64;
  const int b = blockIdx.y, l0 = blockIdx.x * 64;
  const size_t base = ((size_t)b * L + l0) * Nn;
  const size_t ksStride = (size_t)8 * L * Nn;
  Db += base;
  if (PRED) Pred += base;

  __shared__ f16_t OutS[64 * 72];
  const int tid = threadIdx.x;

#pragma unroll
  for (int it = 0; it < 4; ++it) {
    const int idx = it * 256 + tid;
    const int l = idx >> 4, n4 = (idx & 15) * 4;
    const size_t o = (size_t)l * Nn + n4;
    float4 v = *(const float4*)(Part + base + o);
    const float4 p1 = *(const float4*)(Part + base + ksStride + o);
    const float4 p2 = *(const float4*)(Part + base + 2 * ksStride + o);
    const float4 p3 = *(const float4*)(Part + base + 3 * ksStride + o);
    v.x += p1.x; v.y += p1.y; v.z += p1.z; v.w += p1.w;
    v.x += p2.x; v.y += p2.y; v.z += p2.z; v.w += p2.w;
    v.x += p3.x; v.y += p3.y; v.z += p3.z; v.w += p3.w;
    const float4 d = *(const float4*)(Db + o);
    v.x += d.x; v.y += d.y; v.z += d.z; v.w += d.w;
    if (PRED) {
      const float4 p = *(const float4*)(Pred + o);
      v.x += p.x; v.y += p.y; v.z += p.z; v.w += p.w;
    }
    if (FINAL) {
      *(float4*)(OutF + base + o) = v;
    } else {
      OutS[(n4 + 0) * 72 + l] = (f16_t)v.x;
      OutS[(n4 + 1) * 72 + l] = (f16_t)v.y;
      OutS[(n4 + 2) * 72 + l] = (f16_t)v.z;
      OutS[(n4 + 3) * 72 + l] = (f16_t)v.w;
    }
  }
  if (!FINAL) {
    __syncthreads();
    f16_t* dst = UTn + (size_t)b * Nn * L;
#pragma unroll
    for (int it = 0; it < 2; ++it) {
      const int c = it * 256 + tid;
      const int n = c >> 3, lc = (c & 7) * 8;
      *(f16x8*)(dst + (size_t)n * L + l0 + lc) = *(const f16x8*)&OutS[n * 72 + lc];
    }
  }
}

extern "C" void kernel_launch(void* const* d_in, const int* in_sizes, int n_in,
                              void* d_out, int out_size, void* d_ws, size_t ws_size,
                              hipStream_t stream) {
  const float* samples = (const float*)d_in[0];  // [8,1024,3072]
  const float* label   = (const float*)d_in[1];  // [8,1024,64]
  const float* predict = (const float*)d_in[2];  // [8,1024,64]
  const float* W       = (const float*)d_in[3];  // [1024,3072]
  const float* bproj   = (const float*)d_in[4];  // [1024]
  float* out = (float*)d_out;                    // [8,1024,64]

  char* ws = (char*)d_ws;
  // region A [0, 12.58 MB): Whi/Wlo during projection; small buffers after
  f16_t* Whi = (f16_t*)ws;
  f16_t* Wlo = (f16_t*)(ws + 6291456);
  float* mx  = (float*)ws;                       // after gemm1 (W dead)
  float* inv = (float*)(ws + 32768);
  float* Db  = (float*)(ws + 65536);             // 2 MB
  f16_t* DbT = (f16_t*)(ws + 65536 + 2097152);   // 1 MB
  f16_t* UTa = (f16_t*)(ws + 65536 + 3145728);   // 1 MB
  f16_t* UTb = (f16_t*)(ws + 65536 + 4194304);   // 1 MB
  // region B [12.58, 62.9 MB): SampH (50 MB) during gemm1; G (32 MB) after
  f16_t* SampH = (f16_t*)(ws + 12582912);
  float* G     = (float*)(ws + 12582912);
  // region C [62.9, 96.5 MB): Shi/Slo; At aliases Shi, Part aliases Slo
  f16_t* Shi = (f16_t*)(ws + 62914560);
  f16_t* Slo = (f16_t*)(ws + 62914560 + 16777216);
  f16_t* At  = Shi;
  float* Part = (float*)Slo;                     // 8 MB (Slo dead after gemm2)

  const long long LH = 1024LL * 1024;
  const long long LL = 1024LL * 1024;

  // 0) prep: W split + samples convert (fused)
  prep_kernel<<<dim3(27648), 256, 0, stream>>>(W, Whi, Wlo, samples, SampH);

  // 1) S = samples @ W^T + b; epilogue x(1/32)+bias, split-store hi/lo
  gemm_mfma<0><<<dim3(8, 64, 1), 256, 0, stream>>>(
      SampH, Whi, Wlo, bproj, nullptr, Shi, Slo,
      8192, 1024, 3072, 0, 0, 0, 1.0f / 32.0f);

  // 2) G = S S^T - 1e5 I per batch (overwrites SampH region — dead)
  gemm_mfma<1><<<dim3(8, 8, 8), 256, 0, stream>>>(
      Shi, Shi, Slo, nullptr, G, nullptr, nullptr,
      1024, 1024, 1024, LH, LH, LL, 1.0f);

  // 3) row stats, then At = softmax^T fp16 with column stats (Shi dead)
  rowstats_kernel<<<8192, 256, 0, stream>>>(G, mx, inv);
  make_at_kernel<<<8192, 256, 0, stream>>>(G, mx, inv, At);

  // 4) Db fp32 + DbT fp16 (fused)
  make_db_kernel<<<8, 1024, 0, stream>>>(label, Db, DbT);

  // 5) power iteration: each step = split-K partial + finalize
  dim3 gp(16, 8, 4), gf(16, 8);
  iter_part<<<gp, 256, 0, stream>>>(At, DbT, Part);                     // t=2
  iter_fin<0, 0><<<gf, 256, 0, stream>>>(Part, Db, nullptr, UTa, nullptr);
  iter_part<<<gp, 256, 0, stream>>>(At, UTa, Part);                     // t=3
  iter_fin<1, 0><<<gf, 256, 0, stream>>>(Part, Db, predict, UTb, nullptr);
  iter_part<<<gp, 256, 0, stream>>>(At, UTb, Part);                     // t=4
  iter_fin<0, 0><<<gf, 256, 0, stream>>>(Part, Db, nullptr, UTa, nullptr);
  iter_part<<<gp, 256, 0, stream>>>(At, UTa, Part);                     // t=5
  iter_fin<0, 0><<<gf, 256, 0, stream>>>(Part, Db, nullptr, UTb, nullptr);
  iter_part<<<gp, 256, 0, stream>>>(At, UTb, Part);                     // t=6
  iter_fin<0, 1><<<gf, 256, 0, stream>>>(Part, Db, nullptr, nullptr, out);
}